// Round 1
// baseline (7870.490 us; speedup 1.0000x reference)
//
#include <hip/hip_runtime.h>
#include <stdint.h>

#define NND 50000
#define NE  1600000
#define INC 129
#define TP  25
#define NTR 25000
#define MPAD 50048
#define KCAT 224          // 160 (padded x-channels) + 64 (H)
#define NC 192
#define PLANE_U (NND*80)  // uints per time-plane of xT (row stride 80 uints = 160 bf16)

typedef short bf16x8 __attribute__((ext_vector_type(8)));
typedef float f32x4 __attribute__((ext_vector_type(4)));

__device__ __forceinline__ float bf2f(uint32_t h){
  union{uint32_t u; float f;} v; v.u = h<<16; return v.f;
}
__device__ __forceinline__ uint32_t f2bf(float f){
  union{float ff; uint32_t u;} v; v.ff=f;
  return (v.u + 0x7FFFu + ((v.u>>16)&1u))>>16;
}
__device__ __forceinline__ uint32_t pack2(float a, float b){
  return f2bf(a) | (f2bf(b)<<16);
}
__device__ __forceinline__ float sigm(float v){ return 1.f/(1.f+__expf(-v)); }

// ---------------- weight prep: Weff = W_g @ Wl_g[:64], stacked+transposed ----
// BT[j][k], j in 0..191 (z|r|h cols), k in 0..223:
//   k<129   : sum_m W_g[k][m]*Wl_g[m][j%64]
//   129..159: 0 (K pad)
//   160..223: Wl_g[64+(k-160)][j%64] for g in {z,r}; 0 for h (H_tilde uses H*R via G2)
__global__ void k_prep(const float* Wz, const float* bz, const float* Wlz, const float* blz,
                       const float* Wr, const float* br, const float* Wlr, const float* blr,
                       const float* Wh, const float* bh, const float* Wlh, const float* blh,
                       uint16_t* BT, float* ceff, uint16_t* WlhT)
{
  int idx = blockIdx.x*256 + threadIdx.x;
  if (idx < NC*KCAT) {
    int j = idx / KCAT, k = idx - j*KCAT;
    int g = j >> 6, jj = j & 63;
    const float* W  = g==0?Wz :(g==1?Wr :Wh);
    const float* Wl = g==0?Wlz:(g==1?Wlr:Wlh);
    float v = 0.f;
    if (k < INC) {
      for (int m=0;m<64;m++) v += W[k*64+m]*Wl[m*64+jj];
    } else if (k >= 160) {
      int kk = k-160;
      v = (g<2) ? Wl[(64+kk)*64 + jj] : 0.f;
    }
    BT[idx] = (uint16_t)f2bf(v);
  } else if (idx < NC*KCAT + 64*64) {
    int t = idx - NC*KCAT; int j = t>>6, k = t&63;   // WlhT[j][k] = Wl_h[64+k][j]
    WlhT[t] = (uint16_t)f2bf(Wlh[(64+k)*64 + j]);
  } else if (idx < NC*KCAT + 64*64 + NC) {
    int j = idx - NC*KCAT - 64*64;
    int g = j>>6, jj = j&63;
    const float* b  = g==0?bz :(g==1?br :bh);
    const float* Wl = g==0?Wlz:(g==1?Wlr:Wlh);
    const float* bl = g==0?blz:(g==1?blr:blh);
    float v = bl[jj];
    for (int m=0;m<64;m++) v += b[m]*Wl[m*64+jj];
    ceff[j] = v;
  }
}

__global__ void k_probs(const float* att, float* probs){
  if (threadIdx.x==0 && blockIdx.x==0){
    float m=-1e30f;
    for (int i=0;i<TP;i++) m = fmaxf(m, att[i]);
    float e[TP]; float s=0.f;
    for (int i=0;i<TP;i++){ e[i]=__expf(att[i]-m); s+=e[i]; }
    for (int i=0;i<TP;i++) probs[i]=e[i]/s;
  }
}

__global__ void k_hist(const int* eidx, int* deg){
  int e = blockIdx.x*256 + threadIdx.x;
  if (e < NE) atomicAdd(&deg[eidx[NE + e]], 1);   // dst row
}

__global__ void k_dinv(const int* deg, float* dinv){
  int n = blockIdx.x*256 + threadIdx.x;
  if (n < NND) dinv[n] = rsqrtf(1.0f + (float)deg[n]);
}

__global__ void k_scan(const int* deg, int* row_ptr){
  __shared__ int s[1024];
  int tid = threadIdx.x; int off = 0;
  for (int base=0; base<NND; base+=1024){
    int v = (base+tid<NND)? deg[base+tid] : 0;
    s[tid]=v; __syncthreads();
    for (int d=1; d<1024; d<<=1){
      int t = (tid>=d)? s[tid-d] : 0;
      __syncthreads();
      s[tid]+=t; __syncthreads();
    }
    if (base+tid<NND) row_ptr[base+tid] = off + s[tid]-v;
    off += s[1023];
    __syncthreads();
  }
  if (tid==0) row_ptr[NND]=off;
}

__global__ void k_fill(const int* eidx, const int* row_ptr, int* cnt,
                       const float* dinv, int* csr_src, float* csr_w){
  int e = blockIdx.x*256 + threadIdx.x;
  if (e < NE){
    int s = eidx[e], d = eidx[NE+e];
    int pos = row_ptr[d] + atomicAdd(&cnt[d],1);
    csr_src[pos] = s;
    csr_w[pos] = dinv[s]*dinv[d];
  }
}

// x (N,129,25) fp32 -> xT[t][n][c] bf16, c padded to 160 with zeros
__global__ void k_transpose(const float* x, uint32_t* xT){
  int idx = blockIdx.x*256 + threadIdx.x;      // over NND*80
  if (idx >= NND*80) return;
  int n = idx/80, co = idx - n*80;
  int c0 = co*2, c1 = c0+1;
  const float* xr = x + (size_t)n*(INC*TP);
  #pragma unroll
  for (int tt=0; tt<TP; tt++){
    float v0 = (c0<INC)? xr[c0*TP+tt] : 0.f;
    float v1 = (c1<INC)? xr[c1*TP+tt] : 0.f;
    xT[(size_t)tt*PLANE_U + idx] = pack2(v0,v1);
  }
}

// one wave per dst node: AX[d][c] = sum_in w*xT[t][s][c] + dinv[d]^2*xT[t][d][c]
__global__ __launch_bounds__(256) void k_agg(const uint32_t* __restrict__ xTt,
    const int* __restrict__ row_ptr, const int* __restrict__ csr_src,
    const float* __restrict__ csr_w, const float* __restrict__ dinv,
    uint32_t* __restrict__ AX)
{
  int wave = threadIdx.x>>6, lane = threadIdx.x&63;
  int d = blockIdx.x*4 + wave;
  uint32_t* outr = AX + (size_t)d*80;
  if (d >= NND){
    outr[lane]=0; if (lane<16) outr[64+lane]=0;
    return;
  }
  float a0=0.f, a1=0.f, a2=0.f;
  int beg=row_ptr[d], end=row_ptr[d+1];
  for (int i=beg;i<end;i++){
    int s = csr_src[i]; float w = csr_w[i];
    uint32_t u = xTt[(size_t)s*80 + lane];
    a0 += w*bf2f(u&0xFFFFu); a1 += w*bf2f(u>>16);
    if (lane==0){ uint32_t u2 = xTt[(size_t)s*80+64]; a2 += w*bf2f(u2&0xFFFFu); }
  }
  float sn = dinv[d]*dinv[d];
  {
    uint32_t u = xTt[(size_t)d*80+lane];
    a0 += sn*bf2f(u&0xFFFFu); a1 += sn*bf2f(u>>16);
    if (lane==0){ uint32_t u2 = xTt[(size_t)d*80+64]; a2 += sn*bf2f(u2&0xFFFFu); }
  }
  outr[lane] = pack2(a0,a1);
  if (lane==0) outr[64] = pack2(a2,0.f);
  else if (lane<16) outr[64+lane] = 0;
}

// G1: C(N x 192) = [AX | Hbf](N x 224) @ Bcomb(224 x 192) + ceff
// epilogue by col-tile: y=0 -> Z=sigmoid, y=1 -> HR=H*sigmoid, y=2 -> Ph raw
__global__ __launch_bounds__(256) void k_g1(const uint32_t* __restrict__ AX,
    const uint32_t* __restrict__ Hbf, const uint32_t* __restrict__ BT,
    const float* __restrict__ ceff, const float* __restrict__ H,
    float* __restrict__ Z, uint16_t* __restrict__ HR, float* __restrict__ Ph)
{
  __shared__ uint32_t lA[64*116];
  __shared__ uint32_t lB[64*116];
  int tid = threadIdx.x;
  int n0 = blockIdx.x*64;
  int c0 = blockIdx.y*64;
  for (int idx=tid; idx<64*112; idx+=256){
    int r = idx/112, cu = idx - r*112;
    uint32_t va = (cu<80) ? AX[(size_t)(n0+r)*80 + cu]
                          : Hbf[(size_t)(n0+r)*32 + (cu-80)];
    lA[r*116+cu] = va;
    lB[r*116+cu] = BT[(size_t)(c0+r)*112 + cu];
  }
  __syncthreads();
  int wave=tid>>6, lane=tid&63;
  int col16 = lane&15, kgrp = lane>>4;
  int arow = wave*16 + col16;
  f32x4 acc[4] = {};
  #pragma unroll
  for (int kk=0; kk<7; kk++){
    bf16x8 a = *(const bf16x8*)&lA[arow*116 + kk*16 + kgrp*4];
    #pragma unroll
    for (int cc=0; cc<4; cc++){
      bf16x8 b = *(const bf16x8*)&lB[(cc*16 + col16)*116 + kk*16 + kgrp*4];
      acc[cc] = __builtin_amdgcn_mfma_f32_16x16x32_bf16(a,b,acc[cc],0,0,0);
    }
  }
  int rbase = wave*16 + kgrp*4;
  #pragma unroll
  for (int cc=0;cc<4;cc++){
    #pragma unroll
    for (int j=0;j<4;j++){
      int n = n0 + rbase + j;
      if (n >= NND) continue;
      int jl = cc*16 + col16;
      float v = acc[cc][j] + ceff[c0 + jl];
      if (blockIdx.y==0){
        Z[(size_t)n*64+jl] = sigm(v);
      } else if (blockIdx.y==1){
        float r = sigm(v);
        HR[(size_t)n*64+jl] = (uint16_t)f2bf(H[(size_t)n*64+jl]*r);
      } else {
        Ph[(size_t)n*64+jl] = v;
      }
    }
  }
}

// G2: T = HR(N x 64) @ WlhT(64 x 64); Ht=tanh(T+Ph); H=Z*H+(1-Z)*Ht; acc += p_t*H
__global__ __launch_bounds__(256) void k_g2(const uint32_t* __restrict__ HRu,
    const uint32_t* __restrict__ WlhTu, const float* __restrict__ Ph,
    const float* __restrict__ Z, float* __restrict__ H, uint16_t* __restrict__ Hbf,
    float* __restrict__ accum, const float* __restrict__ probs, int t)
{
  __shared__ uint32_t lA[64*36];
  __shared__ uint32_t lB[64*36];
  int tid=threadIdx.x; int n0 = blockIdx.x*64;
  for (int idx=tid; idx<64*32; idx+=256){
    int r=idx>>5, cu=idx&31;
    lA[r*36+cu] = HRu[(size_t)(n0+r)*32+cu];
    lB[r*36+cu] = WlhTu[r*32+cu];
  }
  __syncthreads();
  int wave=tid>>6, lane=tid&63, col16=lane&15, kgrp=lane>>4;
  int arow = wave*16 + col16;
  f32x4 acc[4]={};
  #pragma unroll
  for (int kk=0;kk<2;kk++){
    bf16x8 a = *(const bf16x8*)&lA[arow*36 + kk*16 + kgrp*4];
    #pragma unroll
    for (int cc=0;cc<4;cc++){
      bf16x8 b = *(const bf16x8*)&lB[(cc*16+col16)*36 + kk*16 + kgrp*4];
      acc[cc]=__builtin_amdgcn_mfma_f32_16x16x32_bf16(a,b,acc[cc],0,0,0);
    }
  }
  float pt = probs[t];
  int rbase = wave*16 + kgrp*4;
  #pragma unroll
  for (int cc=0;cc<4;cc++){
    #pragma unroll
    for (int j=0;j<4;j++){
      int n = n0 + rbase + j;
      if (n >= NND) continue;
      int jl = cc*16+col16;
      float pre = acc[cc][j] + Ph[(size_t)n*64+jl];
      float ht = tanhf(pre);
      float z = Z[(size_t)n*64+jl];
      float h = H[(size_t)n*64+jl];
      float hn = z*h + (1.f-z)*ht;
      H[(size_t)n*64+jl]=hn;
      Hbf[(size_t)n*64+jl]=(uint16_t)f2bf(hn);
      accum[(size_t)n*64+jl]+=pt*hn;
    }
  }
}

__global__ void k_out(const int* train_idx, const float* accum, const float* Wo,
                      const float* bo, const float* y, float* out){
  int i = blockIdx.x*256 + threadIdx.x;
  if (i < NTR){
    int n = train_idx[i];
    float s = bo[0];
    const float* ar = accum + (size_t)n*64;
    #pragma unroll
    for (int j=0;j<64;j++) s += ar[j]*Wo[j];
    out[i] = sigm(s);
    out[NTR+i] = y[n];
  }
}

extern "C" void kernel_launch(void* const* d_in, const int* in_sizes, int n_in,
                              void* d_out, int out_size, void* d_ws, size_t ws_size,
                              hipStream_t stream)
{
  const float* x   = (const float*)d_in[0];
  const int*   eix = (const int*)d_in[1];
  const float* y   = (const float*)d_in[2];
  const int*   tri = (const int*)d_in[3];
  const float* Wz  = (const float*)d_in[4];
  const float* bz  = (const float*)d_in[5];
  const float* Wlz = (const float*)d_in[6];
  const float* blz = (const float*)d_in[7];
  const float* Wr  = (const float*)d_in[8];
  const float* br  = (const float*)d_in[9];
  const float* Wlr = (const float*)d_in[10];
  const float* blr = (const float*)d_in[11];
  const float* Wh  = (const float*)d_in[12];
  const float* bh  = (const float*)d_in[13];
  const float* Wlh = (const float*)d_in[14];
  const float* blh = (const float*)d_in[15];
  const float* att = (const float*)d_in[16];
  const float* Wo  = (const float*)d_in[17];
  const float* bo  = (const float*)d_in[18];
  float* out = (float*)d_out;

  char* w = (char*)d_ws;
  size_t off = 0;
  auto alloc = [&](size_t sz)->size_t{ size_t o=off; off=(off+sz+255)&~(size_t)255; return o; };

  // --- zero block (one memset) ---
  size_t zo = off;
  size_t o_deg   = alloc((size_t)NND*4);
  size_t o_cnt   = alloc((size_t)NND*4);
  size_t o_H     = alloc((size_t)MPAD*64*4);
  size_t o_accum = alloc((size_t)MPAD*64*4);
  size_t o_Hbf   = alloc((size_t)MPAD*64*2);
  size_t o_HR    = alloc((size_t)MPAD*64*2);
  size_t zlen = off - zo;
  // --- rest ---
  size_t o_dinv  = alloc((size_t)NND*4);
  size_t o_rp    = alloc((size_t)(NND+1)*4);
  size_t o_csrs  = alloc((size_t)NE*4);
  size_t o_csrw  = alloc((size_t)NE*4);
  size_t o_BT    = alloc((size_t)NC*KCAT*2);
  size_t o_ceff  = alloc((size_t)NC*4);
  size_t o_WlhT  = alloc((size_t)64*64*2);
  size_t o_probs = alloc((size_t)TP*4);
  size_t o_Z     = alloc((size_t)MPAD*64*4);
  size_t o_Ph    = alloc((size_t)MPAD*64*4);
  size_t o_AX    = alloc((size_t)MPAD*80*4);
  size_t o_xT    = alloc((size_t)TP*PLANE_U*4);
  (void)ws_size; (void)in_sizes; (void)n_in; (void)out_size;

  int*      deg   = (int*)(w+o_deg);
  int*      cnt   = (int*)(w+o_cnt);
  float*    H     = (float*)(w+o_H);
  float*    accum = (float*)(w+o_accum);
  uint32_t* Hbf   = (uint32_t*)(w+o_Hbf);
  uint32_t* HR    = (uint32_t*)(w+o_HR);
  float*    dinv  = (float*)(w+o_dinv);
  int*      rp    = (int*)(w+o_rp);
  int*      csrs  = (int*)(w+o_csrs);
  float*    csrw  = (float*)(w+o_csrw);
  uint16_t* BT    = (uint16_t*)(w+o_BT);
  float*    ceff  = (float*)(w+o_ceff);
  uint16_t* WlhT  = (uint16_t*)(w+o_WlhT);
  float*    probs = (float*)(w+o_probs);
  float*    Z     = (float*)(w+o_Z);
  float*    Ph    = (float*)(w+o_Ph);
  uint32_t* AX    = (uint32_t*)(w+o_AX);
  uint32_t* xT    = (uint32_t*)(w+o_xT);

  hipMemsetAsync(w+zo, 0, zlen, stream);

  k_prep<<<(NC*KCAT + 64*64 + NC + 255)/256, 256, 0, stream>>>(
      Wz,bz,Wlz,blz, Wr,br,Wlr,blr, Wh,bh,Wlh,blh, BT, ceff, WlhT);
  k_probs<<<1, 64, 0, stream>>>(att, probs);
  k_hist<<<(NE+255)/256, 256, 0, stream>>>(eix, deg);
  k_dinv<<<(NND+255)/256, 256, 0, stream>>>(deg, dinv);
  k_scan<<<1, 1024, 0, stream>>>(deg, rp);
  k_fill<<<(NE+255)/256, 256, 0, stream>>>(eix, rp, cnt, dinv, csrs, csrw);
  k_transpose<<<(NND*80+255)/256, 256, 0, stream>>>(x, xT);

  for (int t=0; t<TP; t++){
    const uint32_t* xTt = xT + (size_t)t*PLANE_U;
    k_agg<<<MPAD/4, 256, 0, stream>>>(xTt, rp, csrs, csrw, dinv, AX);
    k_g1<<<dim3(MPAD/64,3), 256, 0, stream>>>(AX, Hbf, (const uint32_t*)BT, ceff, H, Z, (uint16_t*)HR, Ph);
    k_g2<<<MPAD/64, 256, 0, stream>>>(HR, (const uint32_t*)WlhT, Ph, Z, H, (uint16_t*)Hbf, accum, probs, t);
  }
  k_out<<<(NTR+255)/256, 256, 0, stream>>>(tri, accum, Wo, bo, y, out);
}

// Round 2
// 5801.067 us; speedup vs baseline: 1.3567x; 1.3567x over previous
//
#include <hip/hip_runtime.h>
#include <stdint.h>

#define NND 50000
#define NE  1600000
#define INC 129
#define TP  25
#define NTR 25000
#define MPAD 50048
#define NC 192
#define PLANE_U (NND*80)  // uints per time-plane of xT (row stride 80 uints = 160 bf16)

typedef short bf16x8 __attribute__((ext_vector_type(8)));
typedef float f32x4 __attribute__((ext_vector_type(4)));

__device__ __forceinline__ float bf2f(uint32_t h){
  union{uint32_t u; float f;} v; v.u = h<<16; return v.f;
}
__device__ __forceinline__ uint32_t f2bf(float f){
  union{float ff; uint32_t u;} v; v.ff=f;
  return (v.u + 0x7FFFu + ((v.u>>16)&1u))>>16;
}
__device__ __forceinline__ uint32_t pack2(float a, float b){
  return f2bf(a) | (f2bf(b)<<16);
}
__device__ __forceinline__ float sigm(float v){ return 1.f/(1.f+__expf(-v)); }

// ---------------- weight prep: Weff = W_g @ Wl_g[:64], stacked+transposed ----
// BT[j][k], j in 0..191 (z|r|h cols), k in 0..223:
//   k<129   : sum_m W_g[k][m]*Wl_g[m][j%64]
//   129..159: 0 (K pad)
//   160..223: Wl_g[64+(k-160)][j%64] for g in {z,r}; 0 for h
__global__ void k_prep(const float* Wz, const float* bz, const float* Wlz, const float* blz,
                       const float* Wr, const float* br, const float* Wlr, const float* blr,
                       const float* Wh, const float* bh, const float* Wlh, const float* blh,
                       uint16_t* BT, float* ceff, uint16_t* WlhT)
{
  int idx = blockIdx.x*256 + threadIdx.x;
  if (idx < NC*224) {
    int j = idx / 224, k = idx - j*224;
    int g = j >> 6, jj = j & 63;
    const float* W  = g==0?Wz :(g==1?Wr :Wh);
    const float* Wl = g==0?Wlz:(g==1?Wlr:Wlh);
    float v = 0.f;
    if (k < INC) {
      for (int m=0;m<64;m++) v += W[k*64+m]*Wl[m*64+jj];
    } else if (k >= 160) {
      int kk = k-160;
      v = (g<2) ? Wl[(64+kk)*64 + jj] : 0.f;
    }
    BT[idx] = (uint16_t)f2bf(v);
  } else if (idx < NC*224 + 64*64) {
    int t = idx - NC*224; int j = t>>6, k = t&63;   // WlhT[j][k] = Wl_h[64+k][j]
    WlhT[t] = (uint16_t)f2bf(Wlh[(64+k)*64 + j]);
  } else if (idx < NC*224 + 64*64 + NC) {
    int j = idx - NC*224 - 64*64;
    int g = j>>6, jj = j&63;
    const float* b  = g==0?bz :(g==1?br :bh);
    const float* Wl = g==0?Wlz:(g==1?Wlr:Wlh);
    const float* bl = g==0?blz:(g==1?blr:blh);
    float v = bl[jj];
    for (int m=0;m<64;m++) v += b[m]*Wl[m*64+jj];
    ceff[j] = v;
  }
}

__global__ void k_probs(const float* att, float* probs){
  if (threadIdx.x==0 && blockIdx.x==0){
    float m=-1e30f;
    for (int i=0;i<TP;i++) m = fmaxf(m, att[i]);
    float e[TP]; float s=0.f;
    for (int i=0;i<TP;i++){ e[i]=__expf(att[i]-m); s+=e[i]; }
    for (int i=0;i<TP;i++) probs[i]=e[i]/s;
  }
}

__global__ void k_hist(const int* eidx, int* deg){
  int e = blockIdx.x*256 + threadIdx.x;
  if (e < NE) atomicAdd(&deg[eidx[NE + e]], 1);   // dst row
}

__global__ void k_dinv(const int* deg, float* dinv){
  int n = blockIdx.x*256 + threadIdx.x;
  if (n < NND) dinv[n] = rsqrtf(1.0f + (float)deg[n]);
}

__global__ void k_scan(const int* deg, int* row_ptr){
  __shared__ int s[1024];
  int tid = threadIdx.x; int off = 0;
  for (int base=0; base<NND; base+=1024){
    int v = (base+tid<NND)? deg[base+tid] : 0;
    s[tid]=v; __syncthreads();
    for (int d=1; d<1024; d<<=1){
      int t = (tid>=d)? s[tid-d] : 0;
      __syncthreads();
      s[tid]+=t; __syncthreads();
    }
    if (base+tid<NND) row_ptr[base+tid] = off + s[tid]-v;
    off += s[1023];
    __syncthreads();
  }
  if (tid==0) row_ptr[NND]=off;
}

__global__ void k_fill(const int* eidx, const int* row_ptr, int* cnt,
                       const float* dinv, int* csr_src, float* csr_w){
  int e = blockIdx.x*256 + threadIdx.x;
  if (e < NE){
    int s = eidx[e], d = eidx[NE+e];
    int pos = row_ptr[d] + atomicAdd(&cnt[d],1);
    csr_src[pos] = s;
    csr_w[pos] = dinv[s]*dinv[d];
  }
}

// x (N,129,25) fp32 -> xT[t][n][c] bf16 (c padded to 160), LDS-tiled per node.
__global__ __launch_bounds__(256) void k_transpose2(const float* __restrict__ x,
                                                    uint32_t* __restrict__ xT){
  __shared__ float lx[3232];           // 129*25 = 3225
  int n = blockIdx.x;
  const float* xr = x + (size_t)n*(INC*TP);
  for (int e=threadIdx.x; e<INC*TP; e+=256) lx[e] = xr[e];
  __syncthreads();
  for (int idx=threadIdx.x; idx<TP*80; idx+=256){
    int t = idx/80, cu = idx - t*80;
    int c0 = cu*2, c1 = c0+1;
    float v0 = (c0<INC)? lx[c0*TP+t] : 0.f;
    float v1 = (c1<INC)? lx[c1*TP+t] : 0.f;
    xT[(size_t)t*PLANE_U + (size_t)n*80 + cu] = pack2(v0,v1);
  }
}

// one wave per dst node: AX[d][c] = sum_in w*xT[t][s][c] + dinv[d]^2*xT[t][d][c]
__global__ __launch_bounds__(256) void k_agg(const uint32_t* __restrict__ xTt,
    const int* __restrict__ row_ptr, const int* __restrict__ csr_src,
    const float* __restrict__ csr_w, const float* __restrict__ dinv,
    uint32_t* __restrict__ AX)
{
  int wave = threadIdx.x>>6, lane = threadIdx.x&63;
  int d = blockIdx.x*4 + wave;
  uint32_t* outr = AX + (size_t)d*80;
  if (d >= NND){
    outr[lane]=0; if (lane<16) outr[64+lane]=0;
    return;
  }
  float a0=0.f, a1=0.f, a2=0.f;
  int beg=row_ptr[d], end=row_ptr[d+1];
  for (int i=beg;i<end;i++){
    int s = csr_src[i]; float w = csr_w[i];
    uint32_t u = xTt[(size_t)s*80 + lane];
    a0 += w*bf2f(u&0xFFFFu); a1 += w*bf2f(u>>16);
    if (lane==0){ uint32_t u2 = xTt[(size_t)s*80+64]; a2 += w*bf2f(u2&0xFFFFu); }
  }
  float sn = dinv[d]*dinv[d];
  {
    uint32_t u = xTt[(size_t)d*80+lane];
    a0 += sn*bf2f(u&0xFFFFu); a1 += sn*bf2f(u>>16);
    if (lane==0){ uint32_t u2 = xTt[(size_t)d*80+64]; a2 += sn*bf2f(u2&0xFFFFu); }
  }
  outr[lane] = pack2(a0,a1);
  if (lane==0) outr[64] = pack2(a2,0.f);
  else if (lane<16) outr[64+lane] = 0;
}

// Fused step: [AX|Hbf](64x224) @ BT(224x192) -> Z,R,Ph in regs;
// HR=H*R -> LDS; HR @ WlhT(64x64); GRU update + attention accum. One block = 64 rows.
__global__ __launch_bounds__(256) void k_step(const uint32_t* __restrict__ AX,
    const uint32_t* __restrict__ Hbf, const uint32_t* __restrict__ BT,
    const float* __restrict__ ceff, const uint32_t* __restrict__ WlhTu,
    float* __restrict__ H, float* __restrict__ accum,
    const float* __restrict__ probs, int t)
{
  __shared__ __align__(16) uint32_t lA[64*116];
  __shared__ __align__(16) uint32_t lB[64*116];
  uint32_t* lW = lA;                    // alias: used only after tile-2 MFMAs
  uint16_t* lHR = (uint16_t*)lB;        // alias: row stride 88 elems (16B mult)
  int tid = threadIdx.x;
  int n0 = blockIdx.x*64;
  int wave=tid>>6, lane=tid&63;
  int col16 = lane&15, kgrp = lane>>4;
  int arow = wave*16 + col16;

  // phase 1: A tile + B tile 0
  for (int idx=tid; idx<64*112; idx+=256){
    int r = idx/112, cu = idx - r*112;
    uint32_t va = (cu<80) ? AX[(size_t)(n0+r)*80 + cu]
                          : Hbf[(size_t)(n0+r)*32 + (cu-80)];
    lA[r*116+cu] = va;
    lB[r*116+cu] = BT[(size_t)r*112 + cu];
  }
  __syncthreads();

  f32x4 accg[3][4] = {};
  #pragma unroll
  for (int g=0; g<3; g++){
    #pragma unroll
    for (int kk=0; kk<7; kk++){
      bf16x8 a = *(const bf16x8*)&lA[arow*116 + kk*16 + kgrp*4];
      #pragma unroll
      for (int cc=0; cc<4; cc++){
        bf16x8 b = *(const bf16x8*)&lB[(cc*16 + col16)*116 + kk*16 + kgrp*4];
        accg[g][cc] = __builtin_amdgcn_mfma_f32_16x16x32_bf16(a,b,accg[g][cc],0,0,0);
      }
    }
    if (g<2){
      __syncthreads();
      for (int idx=tid; idx<64*112; idx+=256){
        int r = idx/112, cu = idx - r*112;
        lB[r*116+cu] = BT[(size_t)(g+1)*64*112 + (size_t)r*112 + cu];
      }
      __syncthreads();
    }
  }
  __syncthreads();   // everyone done with lA/lB before aliasing

  // epilogue A: gates, HR -> LDS; WlhT -> LDS (into lA space)
  int rbase = wave*16 + kgrp*4;
  #pragma unroll
  for (int cc=0;cc<4;cc++){
    #pragma unroll
    for (int j=0;j<4;j++){
      int rl = rbase + j;
      size_t n = (size_t)(n0 + rl);
      int jl = cc*16 + col16;
      float z  = sigm(accg[0][cc][j] + ceff[jl]);
      float r  = sigm(accg[1][cc][j] + ceff[64+jl]);
      float ph = accg[2][cc][j] + ceff[128+jl];
      float h  = H[n*64+jl];
      accg[0][cc][j] = z;
      accg[1][cc][j] = h;
      accg[2][cc][j] = ph;
      lHR[rl*88 + jl] = (uint16_t)f2bf(h*r);
    }
  }
  for (int idx=tid; idx<64*32; idx+=256){
    int r=idx>>5, cu=idx&31;
    lW[r*36+cu] = WlhTu[r*32+cu];
  }
  __syncthreads();

  // GEMM2: HR @ WlhT
  f32x4 acc2[4] = {};
  #pragma unroll
  for (int kk=0;kk<2;kk++){
    bf16x8 a = *(const bf16x8*)&lHR[arow*88 + kk*32 + kgrp*8];
    #pragma unroll
    for (int cc=0;cc<4;cc++){
      bf16x8 b = *(const bf16x8*)&lW[(cc*16+col16)*36 + kk*16 + kgrp*4];
      acc2[cc]=__builtin_amdgcn_mfma_f32_16x16x32_bf16(a,b,acc2[cc],0,0,0);
    }
  }

  // epilogue B: GRU update, H/Hbf/accum
  float pt = probs[t];
  uint16_t* HbfW = (uint16_t*)Hbf;
  #pragma unroll
  for (int cc=0;cc<4;cc++){
    #pragma unroll
    for (int j=0;j<4;j++){
      size_t n = (size_t)(n0 + rbase + j);
      int jl = cc*16+col16;
      float pre = acc2[cc][j] + accg[2][cc][j];
      float ht = tanhf(pre);
      float z = accg[0][cc][j];
      float h = accg[1][cc][j];
      float hn = z*h + (1.f-z)*ht;
      H[n*64+jl]=hn;
      HbfW[n*64+jl]=(uint16_t)f2bf(hn);
      accum[n*64+jl]+=pt*hn;
    }
  }
}

__global__ void k_out(const int* train_idx, const float* accum, const float* Wo,
                      const float* bo, const float* y, float* out){
  int i = blockIdx.x*256 + threadIdx.x;
  if (i < NTR){
    int n = train_idx[i];
    float s = bo[0];
    const float* ar = accum + (size_t)n*64;
    #pragma unroll
    for (int j=0;j<64;j++) s += ar[j]*Wo[j];
    out[i] = sigm(s);
    out[NTR+i] = y[n];
  }
}

extern "C" void kernel_launch(void* const* d_in, const int* in_sizes, int n_in,
                              void* d_out, int out_size, void* d_ws, size_t ws_size,
                              hipStream_t stream)
{
  const float* x   = (const float*)d_in[0];
  const int*   eix = (const int*)d_in[1];
  const float* y   = (const float*)d_in[2];
  const int*   tri = (const int*)d_in[3];
  const float* Wz  = (const float*)d_in[4];
  const float* bz  = (const float*)d_in[5];
  const float* Wlz = (const float*)d_in[6];
  const float* blz = (const float*)d_in[7];
  const float* Wr  = (const float*)d_in[8];
  const float* br  = (const float*)d_in[9];
  const float* Wlr = (const float*)d_in[10];
  const float* blr = (const float*)d_in[11];
  const float* Wh  = (const float*)d_in[12];
  const float* bh  = (const float*)d_in[13];
  const float* Wlh = (const float*)d_in[14];
  const float* blh = (const float*)d_in[15];
  const float* att = (const float*)d_in[16];
  const float* Wo  = (const float*)d_in[17];
  const float* bo  = (const float*)d_in[18];
  float* out = (float*)d_out;

  char* w = (char*)d_ws;
  size_t off = 0;
  auto alloc = [&](size_t sz)->size_t{ size_t o=off; off=(off+sz+255)&~(size_t)255; return o; };

  // --- zero block (one memset) ---
  size_t zo = off;
  size_t o_deg   = alloc((size_t)NND*4);
  size_t o_cnt   = alloc((size_t)NND*4);
  size_t o_H     = alloc((size_t)MPAD*64*4);
  size_t o_accum = alloc((size_t)MPAD*64*4);
  size_t o_Hbf   = alloc((size_t)MPAD*64*2);
  size_t zlen = off - zo;
  // --- rest ---
  size_t o_dinv  = alloc((size_t)NND*4);
  size_t o_rp    = alloc((size_t)(NND+1)*4);
  size_t o_csrs  = alloc((size_t)NE*4);
  size_t o_csrw  = alloc((size_t)NE*4);
  size_t o_BT    = alloc((size_t)NC*224*2);
  size_t o_ceff  = alloc((size_t)NC*4);
  size_t o_WlhT  = alloc((size_t)64*64*2);
  size_t o_probs = alloc((size_t)TP*4);
  size_t o_AX    = alloc((size_t)MPAD*80*4);
  size_t o_xT    = alloc((size_t)TP*PLANE_U*4);
  (void)ws_size; (void)in_sizes; (void)n_in; (void)out_size;

  int*      deg   = (int*)(w+o_deg);
  int*      cnt   = (int*)(w+o_cnt);
  float*    H     = (float*)(w+o_H);
  float*    accum = (float*)(w+o_accum);
  uint32_t* Hbf   = (uint32_t*)(w+o_Hbf);
  float*    dinv  = (float*)(w+o_dinv);
  int*      rp    = (int*)(w+o_rp);
  int*      csrs  = (int*)(w+o_csrs);
  float*    csrw  = (float*)(w+o_csrw);
  uint16_t* BT    = (uint16_t*)(w+o_BT);
  float*    ceff  = (float*)(w+o_ceff);
  uint16_t* WlhT  = (uint16_t*)(w+o_WlhT);
  float*    probs = (float*)(w+o_probs);
  uint32_t* AX    = (uint32_t*)(w+o_AX);
  uint32_t* xT    = (uint32_t*)(w+o_xT);

  hipMemsetAsync(w+zo, 0, zlen, stream);

  k_prep<<<(NC*224 + 64*64 + NC + 255)/256, 256, 0, stream>>>(
      Wz,bz,Wlz,blz, Wr,br,Wlr,blr, Wh,bh,Wlh,blh, BT, ceff, WlhT);
  k_probs<<<1, 64, 0, stream>>>(att, probs);
  k_hist<<<(NE+255)/256, 256, 0, stream>>>(eix, deg);
  k_dinv<<<(NND+255)/256, 256, 0, stream>>>(deg, dinv);
  k_scan<<<1, 1024, 0, stream>>>(deg, rp);
  k_fill<<<(NE+255)/256, 256, 0, stream>>>(eix, rp, cnt, dinv, csrs, csrw);
  k_transpose2<<<NND, 256, 0, stream>>>(x, xT);

  for (int t=0; t<TP; t++){
    const uint32_t* xTt = xT + (size_t)t*PLANE_U;
    k_agg<<<MPAD/4, 256, 0, stream>>>(xTt, rp, csrs, csrw, dinv, AX);
    k_step<<<MPAD/64, 256, 0, stream>>>(AX, Hbf, (const uint32_t*)BT, ceff,
                                        (const uint32_t*)WlhT, H, accum, probs, t);
  }
  k_out<<<(NTR+255)/256, 256, 0, stream>>>(tri, accum, Wo, bo, y, out);
}

// Round 3
// 5461.058 us; speedup vs baseline: 1.4412x; 1.0623x over previous
//
#include <hip/hip_runtime.h>
#include <stdint.h>

#define NND 50000
#define NE  1600000
#define NETOT (NE + NND)      // edges + self loops
#define INC 129
#define TP  25
#define NTR 25000
#define MPAD 50048
#define NC 192
#define NB_SCAN 196           // ceil(50000/256)

typedef short bf16x8 __attribute__((ext_vector_type(8)));
typedef float f32x4 __attribute__((ext_vector_type(4)));

__device__ __forceinline__ float bf2f(uint32_t h){
  union{uint32_t u; float f;} v; v.u = h<<16; return v.f;
}
__device__ __forceinline__ uint32_t f2bf(float f){
  union{float ff; uint32_t u;} v; v.ff=f;
  return (v.u + 0x7FFFu + ((v.u>>16)&1u))>>16;
}
__device__ __forceinline__ uint32_t pack2(float a, float b){
  return f2bf(a) | (f2bf(b)<<16);
}
__device__ __forceinline__ float sigm(float v){ return 1.f/(1.f+__expf(-v)); }

// ---------------- weight prep: Weff = W_g @ Wl_g[:64], stacked+transposed ----
__global__ void k_prep(const float* Wz, const float* bz, const float* Wlz, const float* blz,
                       const float* Wr, const float* br, const float* Wlr, const float* blr,
                       const float* Wh, const float* bh, const float* Wlh, const float* blh,
                       uint16_t* BT, float* ceff, uint16_t* WlhT)
{
  int idx = blockIdx.x*256 + threadIdx.x;
  if (idx < NC*224) {
    int j = idx / 224, k = idx - j*224;
    int g = j >> 6, jj = j & 63;
    const float* W  = g==0?Wz :(g==1?Wr :Wh);
    const float* Wl = g==0?Wlz:(g==1?Wlr:Wlh);
    float v = 0.f;
    if (k < INC) {
      for (int m=0;m<64;m++) v += W[k*64+m]*Wl[m*64+jj];
    } else if (k >= 160) {
      int kk = k-160;
      v = (g<2) ? Wl[(64+kk)*64 + jj] : 0.f;
    }
    BT[idx] = (uint16_t)f2bf(v);
  } else if (idx < NC*224 + 64*64) {
    int t = idx - NC*224; int j = t>>6, k = t&63;   // WlhT[j][k] = Wl_h[64+k][j]
    WlhT[t] = (uint16_t)f2bf(Wlh[(64+k)*64 + j]);
  } else if (idx < NC*224 + 64*64 + NC) {
    int j = idx - NC*224 - 64*64;
    int g = j>>6, jj = j&63;
    const float* b  = g==0?bz :(g==1?br :bh);
    const float* Wl = g==0?Wlz:(g==1?Wlr:Wlh);
    const float* bl = g==0?blz:(g==1?blr:blh);
    float v = bl[jj];
    for (int m=0;m<64;m++) v += b[m]*Wl[m*64+jj];
    ceff[j] = v;
  }
}

__global__ void k_probs(const float* att, float* probs){
  if (threadIdx.x==0 && blockIdx.x==0){
    float m=-1e30f;
    for (int i=0;i<TP;i++) m = fmaxf(m, att[i]);
    float e[TP]; float s=0.f;
    for (int i=0;i<TP;i++){ e[i]=__expf(att[i]-m); s+=e[i]; }
    for (int i=0;i<TP;i++) probs[i]=e[i]/s;
  }
}

__global__ void k_hist(const int* eidx, int* deg){
  int e = blockIdx.x*256 + threadIdx.x;
  if (e < NE) atomicAdd(&deg[eidx[NE + e]], 1);   // dst row
}

__global__ void k_dinv(const int* deg, float* dinv){
  int n = blockIdx.x*256 + threadIdx.x;
  if (n < NND) dinv[n] = rsqrtf(1.0f + (float)deg[n]);
}

// ---- 3-kernel exclusive scan of (deg[i]+1) -> row_ptr (CSR incl. self loops)
__global__ void k_scan1(const int* deg, int* row_ptr, int* bsum){
  __shared__ int s[256];
  int tid = threadIdx.x;
  int i = blockIdx.x*256 + tid;
  int v = (i < NND) ? deg[i]+1 : 0;
  s[tid] = v; __syncthreads();
  for (int d=1; d<256; d<<=1){
    int t = (tid>=d) ? s[tid-d] : 0;
    __syncthreads();
    s[tid] += t; __syncthreads();
  }
  if (i < NND) row_ptr[i] = s[tid] - v;
  if (tid == 255) bsum[blockIdx.x] = s[255];
}
__global__ void k_scan2(int* bsum, int* boff, int* row_ptr){
  __shared__ int s[256];
  int tid = threadIdx.x;
  int v = (tid < NB_SCAN) ? bsum[tid] : 0;
  s[tid] = v; __syncthreads();
  for (int d=1; d<256; d<<=1){
    int t = (tid>=d) ? s[tid-d] : 0;
    __syncthreads();
    s[tid] += t; __syncthreads();
  }
  if (tid < NB_SCAN) boff[tid] = s[tid] - v;
  if (tid == NB_SCAN-1) row_ptr[NND] = s[tid];
}
__global__ void k_scan3(int* row_ptr, const int* boff){
  int i = blockIdx.x*256 + threadIdx.x;
  if (i < NND) row_ptr[i] += boff[blockIdx.x];
}

__global__ void k_fill(const int* eidx, const int* row_ptr, int* cnt,
                       const float* dinv, int2* csr){
  int e = blockIdx.x*256 + threadIdx.x;
  if (e < NE){
    int s = eidx[e], d = eidx[NE+e];
    int pos = row_ptr[d] + atomicAdd(&cnt[d],1);
    int2 ent; ent.x = s;
    float w = dinv[s]*dinv[d];
    ent.y = __float_as_int(w);
    csr[pos] = ent;
  }
}
__global__ void k_self(const int* row_ptr, const float* dinv, int2* csr){
  int n = blockIdx.x*256 + threadIdx.x;
  if (n < NND){
    int2 ent; ent.x = n;
    float w = dinv[n]*dinv[n];
    ent.y = __float_as_int(w);
    csr[row_ptr[n+1]-1] = ent;
  }
}

// x (N,129,25) fp32 -> xT2[t][cblk][n][16 uints] (ch 0..127 bf16) + xlast[t][n] f32
__global__ __launch_bounds__(256) void k_transpose3(const float* __restrict__ x,
                                                    uint32_t* __restrict__ xT2,
                                                    float* __restrict__ xlast){
  __shared__ float lx[3232];           // 129*25 = 3225
  int n = blockIdx.x;
  const float* xr = x + (size_t)n*(INC*TP);
  for (int e=threadIdx.x; e<INC*TP; e+=256) lx[e] = xr[e];
  __syncthreads();
  for (int idx=threadIdx.x; idx<TP*64; idx+=256){
    int t = idx>>6, u = idx&63;
    int c0 = u*2;
    float v0 = lx[c0*TP+t], v1 = lx[(c0+1)*TP+t];
    int cb = u>>4, ul = u&15;
    xT2[(((size_t)t*4 + cb)*NND + n)*16 + ul] = pack2(v0,v1);
  }
  for (int t=threadIdx.x; t<TP; t+=256)
    xlast[(size_t)t*NND + n] = lx[128*TP + t];
}

// wave per dst, 4 edges/iter, one 32-ch (64B) L2-resident table per blockIdx.y
__global__ __launch_bounds__(256) void k_agg(const uint32_t* __restrict__ xT2t,
    const int* __restrict__ rp, const int2* __restrict__ csr,
    uint32_t* __restrict__ AX)
{
  int wave = threadIdx.x>>6, lane = threadIdx.x&63;
  int q = lane>>4, lanelo = lane&15;
  int d = blockIdx.x*4 + wave;
  int cb = blockIdx.y;
  const uint32_t* tbl = xT2t + (size_t)cb*(NND*16);
  int beg = rp[d], end = rp[d+1];
  float a0=0.f, a1=0.f;
  #pragma unroll 2
  for (int i0 = beg; i0 < end; i0 += 4){
    int i = i0 + q;
    bool v = (i < end);
    int2 e = csr[v ? i : i0];          // in-bounds dummy for masked lanes
    int s = v ? e.x : d;
    float w = v ? __int_as_float(e.y) : 0.f;
    uint32_t u = tbl[(size_t)s*16 + lanelo];
    a0 += w*bf2f(u&0xFFFFu);
    a1 += w*bf2f(u>>16);
  }
  a0 += __shfl_xor(a0, 16); a0 += __shfl_xor(a0, 32);
  a1 += __shfl_xor(a1, 16); a1 += __shfl_xor(a1, 32);
  if (q==0) AX[(size_t)d*80 + cb*16 + lanelo] = pack2(a0,a1);
}

// channel 128: thread per dst, gathers from 200KB (L2-resident) f32 plane
__global__ void k_agg_last(const float* __restrict__ xlt,
    const int* __restrict__ rp, const int2* __restrict__ csr,
    uint32_t* __restrict__ AX)
{
  int d = blockIdx.x*256 + threadIdx.x;
  if (d >= NND) return;
  float a = 0.f;
  int beg=rp[d], end=rp[d+1];
  for (int i=beg;i<end;i++){
    int2 e = csr[i];
    a += __int_as_float(e.y)*xlt[e.x];
  }
  AX[(size_t)d*80 + 64] = pack2(a, 0.f);
}

// Fused step: [AX|Hbf](64x224) @ BT(224x192) -> Z,R,Ph in regs;
// HR=H*R -> LDS; HR @ WlhT(64x64); GRU update + attention accum.
__global__ __launch_bounds__(256) void k_step(const uint32_t* __restrict__ AX,
    const uint32_t* __restrict__ Hbf, const uint32_t* __restrict__ BT,
    const float* __restrict__ ceff, const uint32_t* __restrict__ WlhTu,
    float* __restrict__ H, float* __restrict__ accum,
    const float* __restrict__ probs, int t)
{
  __shared__ __align__(16) uint32_t lA[64*116];
  __shared__ __align__(16) uint32_t lB[64*116];
  uint32_t* lW = lA;                    // alias: used only after tile-2 MFMAs
  uint16_t* lHR = (uint16_t*)lB;        // alias: row stride 88 elems
  int tid = threadIdx.x;
  int n0 = blockIdx.x*64;
  int wave=tid>>6, lane=tid&63;
  int col16 = lane&15, kgrp = lane>>4;
  int arow = wave*16 + col16;

  for (int idx=tid; idx<64*112; idx+=256){
    int r = idx/112, cu = idx - r*112;
    uint32_t va = (cu<80) ? AX[(size_t)(n0+r)*80 + cu]
                          : Hbf[(size_t)(n0+r)*32 + (cu-80)];
    lA[r*116+cu] = va;
    lB[r*116+cu] = BT[(size_t)r*112 + cu];
  }
  __syncthreads();

  f32x4 accg[3][4] = {};
  #pragma unroll
  for (int g=0; g<3; g++){
    #pragma unroll
    for (int kk=0; kk<7; kk++){
      bf16x8 a = *(const bf16x8*)&lA[arow*116 + kk*16 + kgrp*4];
      #pragma unroll
      for (int cc=0; cc<4; cc++){
        bf16x8 b = *(const bf16x8*)&lB[(cc*16 + col16)*116 + kk*16 + kgrp*4];
        accg[g][cc] = __builtin_amdgcn_mfma_f32_16x16x32_bf16(a,b,accg[g][cc],0,0,0);
      }
    }
    if (g<2){
      __syncthreads();
      for (int idx=tid; idx<64*112; idx+=256){
        int r = idx/112, cu = idx - r*112;
        lB[r*116+cu] = BT[(size_t)(g+1)*64*112 + (size_t)r*112 + cu];
      }
      __syncthreads();
    }
  }
  __syncthreads();   // everyone done with lA/lB before aliasing

  int rbase = wave*16 + kgrp*4;
  #pragma unroll
  for (int cc=0;cc<4;cc++){
    #pragma unroll
    for (int j=0;j<4;j++){
      int rl = rbase + j;
      size_t n = (size_t)(n0 + rl);
      int jl = cc*16 + col16;
      float z  = sigm(accg[0][cc][j] + ceff[jl]);
      float r  = sigm(accg[1][cc][j] + ceff[64+jl]);
      float ph = accg[2][cc][j] + ceff[128+jl];
      float h  = H[n*64+jl];
      accg[0][cc][j] = z;
      accg[1][cc][j] = h;
      accg[2][cc][j] = ph;
      lHR[rl*88 + jl] = (uint16_t)f2bf(h*r);
    }
  }
  for (int idx=tid; idx<64*32; idx+=256){
    int r=idx>>5, cu=idx&31;
    lW[r*36+cu] = WlhTu[r*32+cu];
  }
  __syncthreads();

  f32x4 acc2[4] = {};
  #pragma unroll
  for (int kk=0;kk<2;kk++){
    bf16x8 a = *(const bf16x8*)&lHR[arow*88 + kk*32 + kgrp*8];
    #pragma unroll
    for (int cc=0;cc<4;cc++){
      bf16x8 b = *(const bf16x8*)&lW[(cc*16+col16)*36 + kk*16 + kgrp*4];
      acc2[cc]=__builtin_amdgcn_mfma_f32_16x16x32_bf16(a,b,acc2[cc],0,0,0);
    }
  }

  float pt = probs[t];
  uint16_t* HbfW = (uint16_t*)Hbf;
  #pragma unroll
  for (int cc=0;cc<4;cc++){
    #pragma unroll
    for (int j=0;j<4;j++){
      size_t n = (size_t)(n0 + rbase + j);
      int jl = cc*16+col16;
      float pre = acc2[cc][j] + accg[2][cc][j];
      float ht = tanhf(pre);
      float z = accg[0][cc][j];
      float h = accg[1][cc][j];
      float hn = z*h + (1.f-z)*ht;
      H[n*64+jl]=hn;
      HbfW[n*64+jl]=(uint16_t)f2bf(hn);
      accum[n*64+jl]+=pt*hn;
    }
  }
}

__global__ void k_out(const int* train_idx, const float* accum, const float* Wo,
                      const float* bo, const float* y, float* out){
  int i = blockIdx.x*256 + threadIdx.x;
  if (i < NTR){
    int n = train_idx[i];
    float s = bo[0];
    const float* ar = accum + (size_t)n*64;
    #pragma unroll
    for (int j=0;j<64;j++) s += ar[j]*Wo[j];
    out[i] = sigm(s);
    out[NTR+i] = y[n];
  }
}

extern "C" void kernel_launch(void* const* d_in, const int* in_sizes, int n_in,
                              void* d_out, int out_size, void* d_ws, size_t ws_size,
                              hipStream_t stream)
{
  const float* x   = (const float*)d_in[0];
  const int*   eix = (const int*)d_in[1];
  const float* y   = (const float*)d_in[2];
  const int*   tri = (const int*)d_in[3];
  const float* Wz  = (const float*)d_in[4];
  const float* bz  = (const float*)d_in[5];
  const float* Wlz = (const float*)d_in[6];
  const float* blz = (const float*)d_in[7];
  const float* Wr  = (const float*)d_in[8];
  const float* br  = (const float*)d_in[9];
  const float* Wlr = (const float*)d_in[10];
  const float* blr = (const float*)d_in[11];
  const float* Wh  = (const float*)d_in[12];
  const float* bh  = (const float*)d_in[13];
  const float* Wlh = (const float*)d_in[14];
  const float* blh = (const float*)d_in[15];
  const float* att = (const float*)d_in[16];
  const float* Wo  = (const float*)d_in[17];
  const float* bo  = (const float*)d_in[18];
  float* out = (float*)d_out;

  char* w = (char*)d_ws;
  size_t off = 0;
  auto alloc = [&](size_t sz)->size_t{ size_t o=off; off=(off+sz+255)&~(size_t)255; return o; };

  // --- zero block (one memset) ---
  size_t zo = off;
  size_t o_deg   = alloc((size_t)NND*4);
  size_t o_cnt   = alloc((size_t)NND*4);
  size_t o_H     = alloc((size_t)MPAD*64*4);
  size_t o_accum = alloc((size_t)MPAD*64*4);
  size_t o_Hbf   = alloc((size_t)MPAD*64*2);
  size_t o_AX    = alloc((size_t)MPAD*80*4);   // pads (uints 65..79) stay zero
  size_t zlen = off - zo;
  // --- rest ---
  size_t o_dinv  = alloc((size_t)NND*4);
  size_t o_rp    = alloc((size_t)(NND+1)*4);
  size_t o_bsum  = alloc((size_t)NB_SCAN*4);
  size_t o_boff  = alloc((size_t)NB_SCAN*4);
  size_t o_csr   = alloc((size_t)(NETOT+8)*8);
  size_t o_BT    = alloc((size_t)NC*224*2);
  size_t o_ceff  = alloc((size_t)NC*4);
  size_t o_WlhT  = alloc((size_t)64*64*2);
  size_t o_probs = alloc((size_t)TP*4);
  size_t o_xT2   = alloc((size_t)TP*4*NND*64);  // 320 MB
  size_t o_xl    = alloc((size_t)TP*NND*4);     // 5 MB
  (void)ws_size; (void)in_sizes; (void)n_in; (void)out_size;

  int*      deg   = (int*)(w+o_deg);
  int*      cnt   = (int*)(w+o_cnt);
  float*    H     = (float*)(w+o_H);
  float*    accum = (float*)(w+o_accum);
  uint32_t* Hbf   = (uint32_t*)(w+o_Hbf);
  uint32_t* AX    = (uint32_t*)(w+o_AX);
  float*    dinv  = (float*)(w+o_dinv);
  int*      rp    = (int*)(w+o_rp);
  int*      bsum  = (int*)(w+o_bsum);
  int*      boff  = (int*)(w+o_boff);
  int2*     csr   = (int2*)(w+o_csr);
  uint16_t* BT    = (uint16_t*)(w+o_BT);
  float*    ceff  = (float*)(w+o_ceff);
  uint16_t* WlhT  = (uint16_t*)(w+o_WlhT);
  float*    probs = (float*)(w+o_probs);
  uint32_t* xT2   = (uint32_t*)(w+o_xT2);
  float*    xlast = (float*)(w+o_xl);

  hipMemsetAsync(w+zo, 0, zlen, stream);

  k_prep<<<(NC*224 + 64*64 + NC + 255)/256, 256, 0, stream>>>(
      Wz,bz,Wlz,blz, Wr,br,Wlr,blr, Wh,bh,Wlh,blh, BT, ceff, WlhT);
  k_probs<<<1, 64, 0, stream>>>(att, probs);
  k_hist<<<(NE+255)/256, 256, 0, stream>>>(eix, deg);
  k_dinv<<<(NND+255)/256, 256, 0, stream>>>(deg, dinv);
  k_scan1<<<NB_SCAN, 256, 0, stream>>>(deg, rp, bsum);
  k_scan2<<<1, 256, 0, stream>>>(bsum, boff, rp);
  k_scan3<<<NB_SCAN, 256, 0, stream>>>(rp, boff);
  k_fill<<<(NE+255)/256, 256, 0, stream>>>(eix, rp, cnt, dinv, csr);
  k_self<<<NB_SCAN, 256, 0, stream>>>(rp, dinv, csr);
  k_transpose3<<<NND, 256, 0, stream>>>(x, xT2, xlast);

  for (int t=0; t<TP; t++){
    const uint32_t* xTt = xT2 + (size_t)t*4*NND*16;
    const float* xlt = xlast + (size_t)t*NND;
    k_agg<<<dim3(12500,4), 256, 0, stream>>>(xTt, rp, csr, AX);
    k_agg_last<<<NB_SCAN, 256, 0, stream>>>(xlt, rp, csr, AX);
    k_step<<<MPAD/64, 256, 0, stream>>>(AX, Hbf, (const uint32_t*)BT, ceff,
                                        (const uint32_t*)WlhT, H, accum, probs, t);
  }
  k_out<<<(NTR+255)/256, 256, 0, stream>>>(tri, accum, Wo, bo, y, out);
}

// Round 4
// 4995.387 us; speedup vs baseline: 1.5756x; 1.0932x over previous
//
#include <hip/hip_runtime.h>
#include <stdint.h>

#define NND 50000
#define NNDP 50016            // table row-stride (sentinel zero row at index NND)
#define NE  1600000
#define INC 129
#define TP  25
#define NTR 25000
#define MPAD 50048
#define NC 192
#define NB_SCAN 196           // ceil(50000/256)
#define CSR_MAX (NE + 4*NND + 64)

typedef short bf16x8 __attribute__((ext_vector_type(8)));
typedef float f32x4 __attribute__((ext_vector_type(4)));

__device__ __forceinline__ uint32_t f2bf(float f){
  union{float ff; uint32_t u;} v; v.ff=f;
  return (v.u + 0x7FFFu + ((v.u>>16)&1u))>>16;
}
__device__ __forceinline__ uint32_t pack2(float a, float b){
  return f2bf(a) | (f2bf(b)<<16);
}
__device__ __forceinline__ float sigm(float v){ return 1.f/(1.f+__expf(-v)); }

// ---------------- weight prep: Weff = W_g @ Wl_g[:64], stacked+transposed ----
__global__ void k_prep(const float* Wz, const float* bz, const float* Wlz, const float* blz,
                       const float* Wr, const float* br, const float* Wlr, const float* blr,
                       const float* Wh, const float* bh, const float* Wlh, const float* blh,
                       uint16_t* BT, float* ceff, uint16_t* WlhT)
{
  int idx = blockIdx.x*256 + threadIdx.x;
  if (idx < NC*224) {
    int j = idx / 224, k = idx - j*224;
    int g = j >> 6, jj = j & 63;
    const float* W  = g==0?Wz :(g==1?Wr :Wh);
    const float* Wl = g==0?Wlz:(g==1?Wlr:Wlh);
    float v = 0.f;
    if (k < INC) {
      for (int m=0;m<64;m++) v += W[k*64+m]*Wl[m*64+jj];
    } else if (k >= 160) {
      int kk = k-160;
      v = (g<2) ? Wl[(64+kk)*64 + jj] : 0.f;
    }
    BT[idx] = (uint16_t)f2bf(v);
  } else if (idx < NC*224 + 64*64) {
    int t = idx - NC*224; int j = t>>6, k = t&63;   // WlhT[j][k] = Wl_h[64+k][j]
    WlhT[t] = (uint16_t)f2bf(Wlh[(64+k)*64 + j]);
  } else if (idx < NC*224 + 64*64 + NC) {
    int j = idx - NC*224 - 64*64;
    int g = j>>6, jj = j&63;
    const float* b  = g==0?bz :(g==1?br :bh);
    const float* Wl = g==0?Wlz:(g==1?Wlr:Wlh);
    const float* bl = g==0?blz:(g==1?blr:blh);
    float v = bl[jj];
    for (int m=0;m<64;m++) v += b[m]*Wl[m*64+jj];
    ceff[j] = v;
  }
}

__global__ void k_probs(const float* att, float* probs){
  if (threadIdx.x==0 && blockIdx.x==0){
    float m=-1e30f;
    for (int i=0;i<TP;i++) m = fmaxf(m, att[i]);
    float e[TP]; float s=0.f;
    for (int i=0;i<TP;i++){ e[i]=__expf(att[i]-m); s+=e[i]; }
    for (int i=0;i<TP;i++) probs[i]=e[i]/s;
  }
}

__global__ void k_hist(const int* eidx, int* deg){
  int e = blockIdx.x*256 + threadIdx.x;
  if (e < NE) atomicAdd(&deg[eidx[NE + e]], 1);   // dst row
}

__global__ void k_dinv(const int* deg, float* dinv){
  int n = blockIdx.x*256 + threadIdx.x;
  if (n < NND) dinv[n] = rsqrtf(1.0f + (float)deg[n]);
}

// ---- scan of padded row sizes p_i = (deg_i+1 rounded up to mult of 4) ----
__global__ void k_scan1(const int* deg, int* row_ptr, int* bsum){
  __shared__ int s[256];
  int tid = threadIdx.x;
  int i = blockIdx.x*256 + tid;
  int v = (i < NND) ? ((deg[i]+4)&~3) : 0;
  s[tid] = v; __syncthreads();
  for (int d=1; d<256; d<<=1){
    int t = (tid>=d) ? s[tid-d] : 0;
    __syncthreads();
    s[tid] += t; __syncthreads();
  }
  if (i < NND) row_ptr[i] = s[tid] - v;
  if (tid == 255) bsum[blockIdx.x] = s[255];
}
__global__ void k_scan2(int* bsum, int* boff, int* row_ptr){
  __shared__ int s[256];
  int tid = threadIdx.x;
  int v = (tid < NB_SCAN) ? bsum[tid] : 0;
  s[tid] = v; __syncthreads();
  for (int d=1; d<256; d<<=1){
    int t = (tid>=d) ? s[tid-d] : 0;
    __syncthreads();
    s[tid] += t; __syncthreads();
  }
  if (tid < NB_SCAN) boff[tid] = s[tid] - v;
  if (tid == NB_SCAN-1) row_ptr[NND] = s[tid];
}
__global__ void k_scan3(int* row_ptr, const int* boff){
  int i = blockIdx.x*256 + threadIdx.x;
  if (i < NND) row_ptr[i] += boff[blockIdx.x];
}

__global__ void k_fill(const int* eidx, const int* rp, int* cnt, uint16_t* csr){
  int e = blockIdx.x*256 + threadIdx.x;
  if (e < NE){
    int s = eidx[e], d = eidx[NE+e];
    int pos = rp[d] + atomicAdd(&cnt[d],1);
    csr[pos] = (uint16_t)s;
  }
}
// self-loop entry + sentinel padding (src=NND -> zero table row)
__global__ void k_self(const int* rp, const int* deg, uint16_t* csr){
  int n = blockIdx.x*256 + threadIdx.x;
  if (n < NND){
    int base = rp[n] + deg[n];
    int endp = rp[n+1];
    csr[base] = (uint16_t)n;
    for (int j=base+1; j<endp; j++) csr[j] = (uint16_t)NND;
  }
}

// x (N,129,25) fp32 -> xs tables pre-scaled by dinv[n]:
//   xT2[t][cblk][n][16 uints]  (ch 0..127, bf16 pairs)
//   xsl[t][n] f32              (ch 128)
__global__ __launch_bounds__(256) void k_transpose3(const float* __restrict__ x,
                                                    const float* __restrict__ dinv,
                                                    uint32_t* __restrict__ xT2,
                                                    float* __restrict__ xsl){
  __shared__ float lx[3232];           // 129*25 = 3225
  int n = blockIdx.x;
  const float* xr = x + (size_t)n*(INC*TP);
  for (int e=threadIdx.x; e<INC*TP; e+=256) lx[e] = xr[e];
  __syncthreads();
  float dv = dinv[n];
  for (int idx=threadIdx.x; idx<TP*64; idx+=256){
    int t = idx>>6, u = idx&63;
    int c0 = u*2;
    float v0 = lx[c0*TP+t]*dv, v1 = lx[(c0+1)*TP+t]*dv;
    int cb = u>>4, ul = u&15;
    xT2[(((size_t)t*4 + cb)*NNDP + n)*16 + ul] = pack2(v0,v1);
  }
  for (int t=threadIdx.x; t<TP; t+=256)
    xsl[(size_t)t*NNDP + n] = dv*lx[128*TP + t];
  if (blockIdx.x == 0){                // zero the sentinel rows
    for (int idx=threadIdx.x; idx<TP*4*16; idx+=256){
      int tc = idx>>4, ul = idx&15;
      xT2[((size_t)tc*NNDP + NND)*16 + ul] = 0u;
    }
    for (int t=threadIdx.x; t<TP; t+=256) xsl[(size_t)t*NNDP + NND] = 0.f;
  }
}

// All-t aggregation. grid (12500, 5, 25): y=cblk (4 = ch128 slice), z = t.
// Wave per dst; 4 edges/iter via one broadcast uint64 CSR load; quarter q
// gathers edge i0+q's 64B row slice; cross-quarter shfl reduce; x dinv[d].
__global__ __launch_bounds__(256) void k_agg(const uint32_t* __restrict__ xT2,
    const float* __restrict__ xsl, const int* __restrict__ rp,
    const uint16_t* __restrict__ csr, const float* __restrict__ dinv,
    uint32_t* __restrict__ AX)
{
  int t = blockIdx.z, cb = blockIdx.y;
  int wave = threadIdx.x>>6, lane = threadIdx.x&63;
  int d = blockIdx.x*4 + wave;
  uint32_t* AXt = AX + (size_t)t*((size_t)MPAD*80);
  int beg = rp[d], end = rp[d+1];
  float dv = dinv[d];
  if (cb < 4){
    int q = lane>>4, ll = lane&15;
    const uint32_t* tbl = xT2 + ((size_t)t*4 + cb)*((size_t)NNDP*16);
    const unsigned long long* c64 = (const unsigned long long*)csr;
    int sh = q*16;
    float a0=0.f, a1=0.f;
    #pragma unroll 2
    for (int i0=beg; i0<end; i0+=4){
      unsigned long long c = __builtin_nontemporal_load(&c64[i0>>2]);
      int s = (int)((c >> sh) & 0xFFFFu);
      uint32_t u = tbl[(size_t)s*16 + ll];
      a0 += __int_as_float((int)(u<<16));
      a1 += __int_as_float((int)(u & 0xFFFF0000u));
    }
    a0 += __shfl_xor(a0,16); a0 += __shfl_xor(a0,32);
    a1 += __shfl_xor(a1,16); a1 += __shfl_xor(a1,32);
    if (q==0)
      __builtin_nontemporal_store(pack2(dv*a0, dv*a1),
                                  &AXt[(size_t)d*80 + cb*16 + ll]);
  } else {
    const float* pl = xsl + (size_t)t*NNDP;
    float a=0.f;
    for (int i=beg+lane; i<end; i+=64) a += pl[(int)csr[i]];
    #pragma unroll
    for (int o=32; o>=1; o>>=1) a += __shfl_xor(a,o);
    if (lane==0) AXt[(size_t)d*80+64] = pack2(dv*a, 0.f);
    else if (lane<16) AXt[(size_t)d*80+64+lane] = 0u;
  }
}

// Fused step: [AX|Hbf](64x224) @ BT(224x192) -> Z,R,Ph in regs;
// HR=H*R -> LDS; HR @ WlhT(64x64); GRU update + attention accum.
__global__ __launch_bounds__(256) void k_step(const uint32_t* __restrict__ AX,
    const uint32_t* __restrict__ Hbf, const uint32_t* __restrict__ BT,
    const float* __restrict__ ceff, const uint32_t* __restrict__ WlhTu,
    float* __restrict__ H, float* __restrict__ accum,
    const float* __restrict__ probs, int t)
{
  __shared__ __align__(16) uint32_t lA[64*116];
  __shared__ __align__(16) uint32_t lB[64*116];
  uint32_t* lW = lA;                    // alias: used only after tile-2 MFMAs
  uint16_t* lHR = (uint16_t*)lB;        // alias: row stride 88 elems
  int tid = threadIdx.x;
  int n0 = blockIdx.x*64;
  int wave=tid>>6, lane=tid&63;
  int col16 = lane&15, kgrp = lane>>4;
  int arow = wave*16 + col16;

  for (int idx=tid; idx<64*112; idx+=256){
    int r = idx/112, cu = idx - r*112;
    uint32_t va = (cu<80) ? AX[(size_t)(n0+r)*80 + cu]
                          : Hbf[(size_t)(n0+r)*32 + (cu-80)];
    lA[r*116+cu] = va;
    lB[r*116+cu] = BT[(size_t)r*112 + cu];
  }
  __syncthreads();

  f32x4 accg[3][4] = {};
  #pragma unroll
  for (int g=0; g<3; g++){
    #pragma unroll
    for (int kk=0; kk<7; kk++){
      bf16x8 a = *(const bf16x8*)&lA[arow*116 + kk*16 + kgrp*4];
      #pragma unroll
      for (int cc=0; cc<4; cc++){
        bf16x8 b = *(const bf16x8*)&lB[(cc*16 + col16)*116 + kk*16 + kgrp*4];
        accg[g][cc] = __builtin_amdgcn_mfma_f32_16x16x32_bf16(a,b,accg[g][cc],0,0,0);
      }
    }
    if (g<2){
      __syncthreads();
      for (int idx=tid; idx<64*112; idx+=256){
        int r = idx/112, cu = idx - r*112;
        lB[r*116+cu] = BT[(size_t)(g+1)*64*112 + (size_t)r*112 + cu];
      }
      __syncthreads();
    }
  }
  __syncthreads();   // everyone done with lA/lB before aliasing

  int rbase = wave*16 + kgrp*4;
  #pragma unroll
  for (int cc=0;cc<4;cc++){
    #pragma unroll
    for (int j=0;j<4;j++){
      int rl = rbase + j;
      size_t n = (size_t)(n0 + rl);
      int jl = cc*16 + col16;
      float z  = sigm(accg[0][cc][j] + ceff[jl]);
      float r  = sigm(accg[1][cc][j] + ceff[64+jl]);
      float ph = accg[2][cc][j] + ceff[128+jl];
      float h  = H[n*64+jl];
      accg[0][cc][j] = z;
      accg[1][cc][j] = h;
      accg[2][cc][j] = ph;
      lHR[rl*88 + jl] = (uint16_t)f2bf(h*r);
    }
  }
  for (int idx=tid; idx<64*32; idx+=256){
    int r=idx>>5, cu=idx&31;
    lW[r*36+cu] = WlhTu[r*32+cu];
  }
  __syncthreads();

  f32x4 acc2[4] = {};
  #pragma unroll
  for (int kk=0;kk<2;kk++){
    bf16x8 a = *(const bf16x8*)&lHR[arow*88 + kk*32 + kgrp*8];
    #pragma unroll
    for (int cc=0;cc<4;cc++){
      bf16x8 b = *(const bf16x8*)&lW[(cc*16+col16)*36 + kk*16 + kgrp*4];
      acc2[cc]=__builtin_amdgcn_mfma_f32_16x16x32_bf16(a,b,acc2[cc],0,0,0);
    }
  }

  float pt = probs[t];
  uint16_t* HbfW = (uint16_t*)Hbf;
  #pragma unroll
  for (int cc=0;cc<4;cc++){
    #pragma unroll
    for (int j=0;j<4;j++){
      size_t n = (size_t)(n0 + rbase + j);
      int jl = cc*16+col16;
      float pre = acc2[cc][j] + accg[2][cc][j];
      float ht = tanhf(pre);
      float z = accg[0][cc][j];
      float h = accg[1][cc][j];
      float hn = z*h + (1.f-z)*ht;
      H[n*64+jl]=hn;
      HbfW[n*64+jl]=(uint16_t)f2bf(hn);
      accum[n*64+jl]+=pt*hn;
    }
  }
}

__global__ void k_out(const int* train_idx, const float* accum, const float* Wo,
                      const float* bo, const float* y, float* out){
  int i = blockIdx.x*256 + threadIdx.x;
  if (i < NTR){
    int n = train_idx[i];
    float s = bo[0];
    const float* ar = accum + (size_t)n*64;
    #pragma unroll
    for (int j=0;j<64;j++) s += ar[j]*Wo[j];
    out[i] = sigm(s);
    out[NTR+i] = y[n];
  }
}

extern "C" void kernel_launch(void* const* d_in, const int* in_sizes, int n_in,
                              void* d_out, int out_size, void* d_ws, size_t ws_size,
                              hipStream_t stream)
{
  const float* x   = (const float*)d_in[0];
  const int*   eix = (const int*)d_in[1];
  const float* y   = (const float*)d_in[2];
  const int*   tri = (const int*)d_in[3];
  const float* Wz  = (const float*)d_in[4];
  const float* bz  = (const float*)d_in[5];
  const float* Wlz = (const float*)d_in[6];
  const float* blz = (const float*)d_in[7];
  const float* Wr  = (const float*)d_in[8];
  const float* br  = (const float*)d_in[9];
  const float* Wlr = (const float*)d_in[10];
  const float* blr = (const float*)d_in[11];
  const float* Wh  = (const float*)d_in[12];
  const float* bh  = (const float*)d_in[13];
  const float* Wlh = (const float*)d_in[14];
  const float* blh = (const float*)d_in[15];
  const float* att = (const float*)d_in[16];
  const float* Wo  = (const float*)d_in[17];
  const float* bo  = (const float*)d_in[18];
  float* out = (float*)d_out;

  char* w = (char*)d_ws;
  size_t off = 0;
  auto alloc = [&](size_t sz)->size_t{ size_t o=off; off=(off+sz+255)&~(size_t)255; return o; };

  // --- zero block (one memset) ---
  size_t zo = off;
  size_t o_deg   = alloc((size_t)NND*4);
  size_t o_cnt   = alloc((size_t)NND*4);
  size_t o_H     = alloc((size_t)MPAD*64*4);
  size_t o_accum = alloc((size_t)MPAD*64*4);
  size_t o_Hbf   = alloc((size_t)MPAD*64*2);
  size_t zlen = off - zo;
  // --- rest ---
  size_t o_dinv  = alloc((size_t)NND*4);
  size_t o_rp    = alloc((size_t)(NND+1)*4);
  size_t o_bsum  = alloc((size_t)NB_SCAN*4);
  size_t o_boff  = alloc((size_t)NB_SCAN*4);
  size_t o_csr   = alloc((size_t)CSR_MAX*2);
  size_t o_BT    = alloc((size_t)NC*224*2);
  size_t o_ceff  = alloc((size_t)NC*4);
  size_t o_WlhT  = alloc((size_t)64*64*2);
  size_t o_probs = alloc((size_t)TP*4);
  size_t o_AX    = alloc((size_t)TP*MPAD*80*4);   // 400 MB, all t
  size_t o_xT2   = alloc((size_t)TP*4*NNDP*64);   // 320 MB
  size_t o_xl    = alloc((size_t)TP*NNDP*4);      // 5 MB
  (void)ws_size; (void)in_sizes; (void)n_in; (void)out_size;

  int*      deg   = (int*)(w+o_deg);
  int*      cnt   = (int*)(w+o_cnt);
  float*    H     = (float*)(w+o_H);
  float*    accum = (float*)(w+o_accum);
  uint32_t* Hbf   = (uint32_t*)(w+o_Hbf);
  float*    dinv  = (float*)(w+o_dinv);
  int*      rp    = (int*)(w+o_rp);
  int*      bsum  = (int*)(w+o_bsum);
  int*      boff  = (int*)(w+o_boff);
  uint16_t* csr   = (uint16_t*)(w+o_csr);
  uint16_t* BT    = (uint16_t*)(w+o_BT);
  float*    ceff  = (float*)(w+o_ceff);
  uint16_t* WlhT  = (uint16_t*)(w+o_WlhT);
  float*    probs = (float*)(w+o_probs);
  uint32_t* AX    = (uint32_t*)(w+o_AX);
  uint32_t* xT2   = (uint32_t*)(w+o_xT2);
  float*    xsl   = (float*)(w+o_xl);

  hipMemsetAsync(w+zo, 0, zlen, stream);

  k_prep<<<(NC*224 + 64*64 + NC + 255)/256, 256, 0, stream>>>(
      Wz,bz,Wlz,blz, Wr,br,Wlr,blr, Wh,bh,Wlh,blh, BT, ceff, WlhT);
  k_probs<<<1, 64, 0, stream>>>(att, probs);
  k_hist<<<(NE+255)/256, 256, 0, stream>>>(eix, deg);
  k_dinv<<<(NND+255)/256, 256, 0, stream>>>(deg, dinv);
  k_scan1<<<NB_SCAN, 256, 0, stream>>>(deg, rp, bsum);
  k_scan2<<<1, 256, 0, stream>>>(bsum, boff, rp);
  k_scan3<<<NB_SCAN, 256, 0, stream>>>(rp, boff);
  k_fill<<<(NE+255)/256, 256, 0, stream>>>(eix, rp, cnt, csr);
  k_self<<<NB_SCAN, 256, 0, stream>>>(rp, deg, csr);
  k_transpose3<<<NND, 256, 0, stream>>>(x, dinv, xT2, xsl);

  k_agg<<<dim3(12500,5,TP), 256, 0, stream>>>(xT2, xsl, rp, csr, dinv, AX);

  for (int t=0; t<TP; t++){
    k_step<<<MPAD/64, 256, 0, stream>>>(AX + (size_t)t*MPAD*80, Hbf,
                                        (const uint32_t*)BT, ceff,
                                        (const uint32_t*)WlhT, H, accum, probs, t);
  }
  k_out<<<(NTR+255)/256, 256, 0, stream>>>(tri, accum, Wo, bo, y, out);
}

// Round 5
// 3485.084 us; speedup vs baseline: 2.2583x; 1.4334x over previous
//
#include <hip/hip_runtime.h>
#include <stdint.h>

#define NND 50000
#define NNDP 50016            // table row-stride (sentinel zero row at index NND)
#define NE  1600000
#define INC 129
#define TP  25
#define NTR 25000
#define MPAD 50048
#define NC 192
#define NB_SCAN 196           // ceil(50000/256)
#define CSR_MAX (NE + 8*NND + 128)

typedef short bf16x8 __attribute__((ext_vector_type(8)));
typedef float f32x4 __attribute__((ext_vector_type(4)));

__device__ __forceinline__ uint32_t f2bf(float f){
  union{float ff; uint32_t u;} v; v.ff=f;
  return (v.u + 0x7FFFu + ((v.u>>16)&1u))>>16;
}
__device__ __forceinline__ uint32_t pack2(float a, float b){
  return f2bf(a) | (f2bf(b)<<16);
}
__device__ __forceinline__ float sigm(float v){ return 1.f/(1.f+__expf(-v)); }

// ---------------- weight prep: Weff = W_g @ Wl_g[:64], stacked+transposed ----
__global__ void k_prep(const float* Wz, const float* bz, const float* Wlz, const float* blz,
                       const float* Wr, const float* br, const float* Wlr, const float* blr,
                       const float* Wh, const float* bh, const float* Wlh, const float* blh,
                       uint16_t* BT, float* ceff, uint16_t* WlhT)
{
  int idx = blockIdx.x*256 + threadIdx.x;
  if (idx < NC*224) {
    int j = idx / 224, k = idx - j*224;
    int g = j >> 6, jj = j & 63;
    const float* W  = g==0?Wz :(g==1?Wr :Wh);
    const float* Wl = g==0?Wlz:(g==1?Wlr:Wlh);
    float v = 0.f;
    if (k < INC) {
      for (int m=0;m<64;m++) v += W[k*64+m]*Wl[m*64+jj];
    } else if (k >= 160) {
      int kk = k-160;
      v = (g<2) ? Wl[(64+kk)*64 + jj] : 0.f;
    }
    BT[idx] = (uint16_t)f2bf(v);
  } else if (idx < NC*224 + 64*64) {
    int t = idx - NC*224; int j = t>>6, k = t&63;   // WlhT[j][k] = Wl_h[64+k][j]
    WlhT[t] = (uint16_t)f2bf(Wlh[(64+k)*64 + j]);
  } else if (idx < NC*224 + 64*64 + NC) {
    int j = idx - NC*224 - 64*64;
    int g = j>>6, jj = j&63;
    const float* b  = g==0?bz :(g==1?br :bh);
    const float* Wl = g==0?Wlz:(g==1?Wlr:Wlh);
    const float* bl = g==0?blz:(g==1?blr:blh);
    float v = bl[jj];
    for (int m=0;m<64;m++) v += b[m]*Wl[m*64+jj];
    ceff[j] = v;
  }
}

__global__ void k_probs(const float* att, float* probs){
  if (threadIdx.x==0 && blockIdx.x==0){
    float m=-1e30f;
    for (int i=0;i<TP;i++) m = fmaxf(m, att[i]);
    float e[TP]; float s=0.f;
    for (int i=0;i<TP;i++){ e[i]=__expf(att[i]-m); s+=e[i]; }
    for (int i=0;i<TP;i++) probs[i]=e[i]/s;
  }
}

__global__ void k_hist(const int* eidx, int* deg){
  int e = blockIdx.x*256 + threadIdx.x;
  if (e < NE) atomicAdd(&deg[eidx[NE + e]], 1);   // dst row
}

__global__ void k_dinv(const int* deg, float* dinv){
  int n = blockIdx.x*256 + threadIdx.x;
  if (n < NND) dinv[n] = rsqrtf(1.0f + (float)deg[n]);
}

// ---- scan of padded row sizes p_i = (deg_i+1 rounded up to mult of 8) ----
__global__ void k_scan1(const int* deg, int* row_ptr, int* bsum){
  __shared__ int s[256];
  int tid = threadIdx.x;
  int i = blockIdx.x*256 + tid;
  int v = (i < NND) ? ((deg[i]+8)&~7) : 0;
  s[tid] = v; __syncthreads();
  for (int d=1; d<256; d<<=1){
    int t = (tid>=d) ? s[tid-d] : 0;
    __syncthreads();
    s[tid] += t; __syncthreads();
  }
  if (i < NND) row_ptr[i] = s[tid] - v;
  if (tid == 255) bsum[blockIdx.x] = s[255];
}
__global__ void k_scan2(int* bsum, int* boff, int* row_ptr){
  __shared__ int s[256];
  int tid = threadIdx.x;
  int v = (tid < NB_SCAN) ? bsum[tid] : 0;
  s[tid] = v; __syncthreads();
  for (int d=1; d<256; d<<=1){
    int t = (tid>=d) ? s[tid-d] : 0;
    __syncthreads();
    s[tid] += t; __syncthreads();
  }
  if (tid < NB_SCAN) boff[tid] = s[tid] - v;
  if (tid == NB_SCAN-1) row_ptr[NND] = s[tid];
}
__global__ void k_scan3(int* row_ptr, const int* boff){
  int i = blockIdx.x*256 + threadIdx.x;
  if (i < NND) row_ptr[i] += boff[blockIdx.x];
}

__global__ void k_fill(const int* eidx, const int* rp, int* cnt, uint16_t* csr){
  int e = blockIdx.x*256 + threadIdx.x;
  if (e < NE){
    int s = eidx[e], d = eidx[NE+e];
    int pos = rp[d] + atomicAdd(&cnt[d],1);
    csr[pos] = (uint16_t)s;
  }
}
// self-loop entry + sentinel padding (src=NND -> zero table row)
__global__ void k_self(const int* rp, const int* deg, uint16_t* csr){
  int n = blockIdx.x*256 + threadIdx.x;
  if (n < NND){
    int base = rp[n] + deg[n];
    int endp = rp[n+1];
    csr[base] = (uint16_t)n;
    for (int j=base+1; j<endp; j++) csr[j] = (uint16_t)NND;
  }
}

// x (N,129,25) fp32 -> xs tables pre-scaled by dinv[n]:
//   xT2[t][cblk][n][16 uints]  (ch 0..127, bf16 pairs)
//   xsl[t][n] f32              (ch 128)
__global__ __launch_bounds__(256) void k_transpose3(const float* __restrict__ x,
                                                    const float* __restrict__ dinv,
                                                    uint32_t* __restrict__ xT2,
                                                    float* __restrict__ xsl){
  __shared__ float lx[3232];           // 129*25 = 3225
  int n = blockIdx.x;
  const float* xr = x + (size_t)n*(INC*TP);
  for (int e=threadIdx.x; e<INC*TP; e+=256) lx[e] = xr[e];
  __syncthreads();
  float dv = dinv[n];
  for (int idx=threadIdx.x; idx<TP*64; idx+=256){
    int t = idx>>6, u = idx&63;
    int c0 = u*2;
    float v0 = lx[c0*TP+t]*dv, v1 = lx[(c0+1)*TP+t]*dv;
    int cb = u>>4, ul = u&15;
    xT2[(((size_t)t*4 + cb)*NNDP + n)*16 + ul] = pack2(v0,v1);
  }
  for (int t=threadIdx.x; t<TP; t+=256)
    xsl[(size_t)t*NNDP + n] = dv*lx[128*TP + t];
  if (blockIdx.x == 0){                // zero the sentinel rows
    for (int idx=threadIdx.x; idx<TP*4*16; idx+=256){
      int tc = idx>>4, ul = idx&15;
      xT2[((size_t)tc*NNDP + NND)*16 + ul] = 0u;
    }
    for (int t=threadIdx.x; t<TP; t+=256) xsl[(size_t)t*NNDP + NND] = 0.f;
  }
}

// All-t aggregation. grid (12500, 5, 25): y=cblk (4 = ch128 slice), z = t.
// Wave per dst; 8 edges/iter via one aligned 16B CSR load (rows padded to 8);
// 2 independent 64B gathers per iter, unroll 4 -> ~8 gathers in flight.
__global__ __launch_bounds__(256) void k_agg(const uint32_t* __restrict__ xT2,
    const float* __restrict__ xsl, const int* __restrict__ rp,
    const uint16_t* __restrict__ csr, const float* __restrict__ dinv,
    uint32_t* __restrict__ AX)
{
  int t = blockIdx.z, cb = blockIdx.y;
  int wave = threadIdx.x>>6, lane = threadIdx.x&63;
  int d = blockIdx.x*4 + wave;
  uint32_t* AXt = AX + (size_t)t*((size_t)MPAD*80);
  int beg = rp[d], end = rp[d+1];
  float dv = dinv[d];
  if (cb < 4){
    int q = lane>>4, ll = lane&15;
    const uint32_t* tbl = xT2 + ((size_t)t*4 + cb)*((size_t)NNDP*16);
    const ulonglong2* c128 = (const ulonglong2*)csr;
    int sh = q*16;
    float a0=0.f, a1=0.f;
    #pragma unroll 4
    for (int i0=beg; i0<end; i0+=8){
      ulonglong2 c = c128[i0>>3];
      int s0 = (int)((c.x >> sh) & 0xFFFFu);
      int s1 = (int)((c.y >> sh) & 0xFFFFu);
      uint32_t u0 = tbl[(size_t)s0*16 + ll];
      uint32_t u1 = tbl[(size_t)s1*16 + ll];
      a0 += __int_as_float((int)(u0<<16));
      a1 += __int_as_float((int)(u0 & 0xFFFF0000u));
      a0 += __int_as_float((int)(u1<<16));
      a1 += __int_as_float((int)(u1 & 0xFFFF0000u));
    }
    a0 += __shfl_xor(a0,16); a0 += __shfl_xor(a0,32);
    a1 += __shfl_xor(a1,16); a1 += __shfl_xor(a1,32);
    if (q==0)
      __builtin_nontemporal_store(pack2(dv*a0, dv*a1),
                                  &AXt[(size_t)d*80 + cb*16 + ll]);
  } else {
    const float* pl = xsl + (size_t)t*NNDP;
    float a=0.f;
    for (int i=beg+lane; i<end; i+=64) a += pl[(int)csr[i]];
    #pragma unroll
    for (int o=32; o>=1; o>>=1) a += __shfl_xor(a,o);
    if (lane==0) AXt[(size_t)d*80+64] = pack2(dv*a, 0.f);
    else if (lane<16) AXt[(size_t)d*80+64+lane] = 0u;
  }
}

// Fused step: [AX|Hbf](64x224) @ BT(224x192) -> Z,R,Ph in regs;
// HR=H*R -> LDS; HR @ WlhT(64x64); GRU update + attention accum.
__global__ __launch_bounds__(256) void k_step(const uint32_t* __restrict__ AX,
    const uint32_t* __restrict__ Hbf, const uint32_t* __restrict__ BT,
    const float* __restrict__ ceff, const uint32_t* __restrict__ WlhTu,
    float* __restrict__ H, float* __restrict__ accum,
    const float* __restrict__ probs, int t)
{
  __shared__ __align__(16) uint32_t lA[64*116];
  __shared__ __align__(16) uint32_t lB[64*116];
  uint32_t* lW = lA;                    // alias: used only after tile-2 MFMAs
  uint16_t* lHR = (uint16_t*)lB;        // alias: row stride 88 elems
  int tid = threadIdx.x;
  int n0 = blockIdx.x*64;
  int wave=tid>>6, lane=tid&63;
  int col16 = lane&15, kgrp = lane>>4;
  int arow = wave*16 + col16;

  for (int idx=tid; idx<64*112; idx+=256){
    int r = idx/112, cu = idx - r*112;
    uint32_t va = (cu<80) ? AX[(size_t)(n0+r)*80 + cu]
                          : Hbf[(size_t)(n0+r)*32 + (cu-80)];
    lA[r*116+cu] = va;
    lB[r*116+cu] = BT[(size_t)r*112 + cu];
  }
  __syncthreads();

  f32x4 accg[3][4] = {};
  #pragma unroll
  for (int g=0; g<3; g++){
    #pragma unroll
    for (int kk=0; kk<7; kk++){
      bf16x8 a = *(const bf16x8*)&lA[arow*116 + kk*16 + kgrp*4];
      #pragma unroll
      for (int cc=0; cc<4; cc++){
        bf16x8 b = *(const bf16x8*)&lB[(cc*16 + col16)*116 + kk*16 + kgrp*4];
        accg[g][cc] = __builtin_amdgcn_mfma_f32_16x16x32_bf16(a,b,accg[g][cc],0,0,0);
      }
    }
    if (g<2){
      __syncthreads();
      for (int idx=tid; idx<64*112; idx+=256){
        int r = idx/112, cu = idx - r*112;
        lB[r*116+cu] = BT[(size_t)(g+1)*64*112 + (size_t)r*112 + cu];
      }
      __syncthreads();
    }
  }
  __syncthreads();   // everyone done with lA/lB before aliasing

  int rbase = wave*16 + kgrp*4;
  #pragma unroll
  for (int cc=0;cc<4;cc++){
    #pragma unroll
    for (int j=0;j<4;j++){
      int rl = rbase + j;
      size_t n = (size_t)(n0 + rl);
      int jl = cc*16 + col16;
      float z  = sigm(accg[0][cc][j] + ceff[jl]);
      float r  = sigm(accg[1][cc][j] + ceff[64+jl]);
      float ph = accg[2][cc][j] + ceff[128+jl];
      float h  = H[n*64+jl];
      accg[0][cc][j] = z;
      accg[1][cc][j] = h;
      accg[2][cc][j] = ph;
      lHR[rl*88 + jl] = (uint16_t)f2bf(h*r);
    }
  }
  for (int idx=tid; idx<64*32; idx+=256){
    int r=idx>>5, cu=idx&31;
    lW[r*36+cu] = WlhTu[r*32+cu];
  }
  __syncthreads();

  f32x4 acc2[4] = {};
  #pragma unroll
  for (int kk=0;kk<2;kk++){
    bf16x8 a = *(const bf16x8*)&lHR[arow*88 + kk*32 + kgrp*8];
    #pragma unroll
    for (int cc=0;cc<4;cc++){
      bf16x8 b = *(const bf16x8*)&lW[(cc*16+col16)*36 + kk*16 + kgrp*4];
      acc2[cc]=__builtin_amdgcn_mfma_f32_16x16x32_bf16(a,b,acc2[cc],0,0,0);
    }
  }

  float pt = probs[t];
  uint16_t* HbfW = (uint16_t*)Hbf;
  #pragma unroll
  for (int cc=0;cc<4;cc++){
    #pragma unroll
    for (int j=0;j<4;j++){
      size_t n = (size_t)(n0 + rbase + j);
      int jl = cc*16+col16;
      float pre = acc2[cc][j] + accg[2][cc][j];
      float ht = tanhf(pre);
      float z = accg[0][cc][j];
      float h = accg[1][cc][j];
      float hn = z*h + (1.f-z)*ht;
      H[n*64+jl]=hn;
      HbfW[n*64+jl]=(uint16_t)f2bf(hn);
      accum[n*64+jl]+=pt*hn;
    }
  }
}

__global__ void k_out(const int* train_idx, const float* accum, const float* Wo,
                      const float* bo, const float* y, float* out){
  int i = blockIdx.x*256 + threadIdx.x;
  if (i < NTR){
    int n = train_idx[i];
    float s = bo[0];
    const float* ar = accum + (size_t)n*64;
    #pragma unroll
    for (int j=0;j<64;j++) s += ar[j]*Wo[j];
    out[i] = sigm(s);
    out[NTR+i] = y[n];
  }
}

extern "C" void kernel_launch(void* const* d_in, const int* in_sizes, int n_in,
                              void* d_out, int out_size, void* d_ws, size_t ws_size,
                              hipStream_t stream)
{
  const float* x   = (const float*)d_in[0];
  const int*   eix = (const int*)d_in[1];
  const float* y   = (const float*)d_in[2];
  const int*   tri = (const int*)d_in[3];
  const float* Wz  = (const float*)d_in[4];
  const float* bz  = (const float*)d_in[5];
  const float* Wlz = (const float*)d_in[6];
  const float* blz = (const float*)d_in[7];
  const float* Wr  = (const float*)d_in[8];
  const float* br  = (const float*)d_in[9];
  const float* Wlr = (const float*)d_in[10];
  const float* blr = (const float*)d_in[11];
  const float* Wh  = (const float*)d_in[12];
  const float* bh  = (const float*)d_in[13];
  const float* Wlh = (const float*)d_in[14];
  const float* blh = (const float*)d_in[15];
  const float* att = (const float*)d_in[16];
  const float* Wo  = (const float*)d_in[17];
  const float* bo  = (const float*)d_in[18];
  float* out = (float*)d_out;

  char* w = (char*)d_ws;
  size_t off = 0;
  auto alloc = [&](size_t sz)->size_t{ size_t o=off; off=(off+sz+255)&~(size_t)255; return o; };

  // --- zero block (one memset) ---
  size_t zo = off;
  size_t o_deg   = alloc((size_t)NND*4);
  size_t o_cnt   = alloc((size_t)NND*4);
  size_t o_H     = alloc((size_t)MPAD*64*4);
  size_t o_accum = alloc((size_t)MPAD*64*4);
  size_t o_Hbf   = alloc((size_t)MPAD*64*2);
  size_t zlen = off - zo;
  // --- rest ---
  size_t o_dinv  = alloc((size_t)NND*4);
  size_t o_rp    = alloc((size_t)(NND+1)*4);
  size_t o_bsum  = alloc((size_t)NB_SCAN*4);
  size_t o_boff  = alloc((size_t)NB_SCAN*4);
  size_t o_csr   = alloc((size_t)CSR_MAX*2);
  size_t o_BT    = alloc((size_t)NC*224*2);
  size_t o_ceff  = alloc((size_t)NC*4);
  size_t o_WlhT  = alloc((size_t)64*64*2);
  size_t o_probs = alloc((size_t)TP*4);
  size_t o_AX    = alloc((size_t)TP*MPAD*80*4);   // 400 MB, all t
  size_t o_xT2   = alloc((size_t)TP*4*NNDP*64);   // 320 MB
  size_t o_xl    = alloc((size_t)TP*NNDP*4);      // 5 MB
  (void)ws_size; (void)in_sizes; (void)n_in; (void)out_size;

  int*      deg   = (int*)(w+o_deg);
  int*      cnt   = (int*)(w+o_cnt);
  float*    H     = (float*)(w+o_H);
  float*    accum = (float*)(w+o_accum);
  uint32_t* Hbf   = (uint32_t*)(w+o_Hbf);
  float*    dinv  = (float*)(w+o_dinv);
  int*      rp    = (int*)(w+o_rp);
  int*      bsum  = (int*)(w+o_bsum);
  int*      boff  = (int*)(w+o_boff);
  uint16_t* csr   = (uint16_t*)(w+o_csr);
  uint16_t* BT    = (uint16_t*)(w+o_BT);
  float*    ceff  = (float*)(w+o_ceff);
  uint16_t* WlhT  = (uint16_t*)(w+o_WlhT);
  float*    probs = (float*)(w+o_probs);
  uint32_t* AX    = (uint32_t*)(w+o_AX);
  uint32_t* xT2   = (uint32_t*)(w+o_xT2);
  float*    xsl   = (float*)(w+o_xl);

  hipMemsetAsync(w+zo, 0, zlen, stream);

  k_prep<<<(NC*224 + 64*64 + NC + 255)/256, 256, 0, stream>>>(
      Wz,bz,Wlz,blz, Wr,br,Wlr,blr, Wh,bh,Wlh,blh, BT, ceff, WlhT);
  k_probs<<<1, 64, 0, stream>>>(att, probs);
  k_hist<<<(NE+255)/256, 256, 0, stream>>>(eix, deg);
  k_dinv<<<(NND+255)/256, 256, 0, stream>>>(deg, dinv);
  k_scan1<<<NB_SCAN, 256, 0, stream>>>(deg, rp, bsum);
  k_scan2<<<1, 256, 0, stream>>>(bsum, boff, rp);
  k_scan3<<<NB_SCAN, 256, 0, stream>>>(rp, boff);
  k_fill<<<(NE+255)/256, 256, 0, stream>>>(eix, rp, cnt, csr);
  k_self<<<NB_SCAN, 256, 0, stream>>>(rp, deg, csr);
  k_transpose3<<<NND, 256, 0, stream>>>(x, dinv, xT2, xsl);

  k_agg<<<dim3(12500,5,TP), 256, 0, stream>>>(xT2, xsl, rp, csr, dinv, AX);

  for (int t=0; t<TP; t++){
    k_step<<<MPAD/64, 256, 0, stream>>>(AX + (size_t)t*MPAD*80, Hbf,
                                        (const uint32_t*)BT, ceff,
                                        (const uint32_t*)WlhT, H, accum, probs, t);
  }
  k_out<<<(NTR+255)/256, 256, 0, stream>>>(tri, accum, Wo, bo, y, out);
}

// Round 6
// 2358.937 us; speedup vs baseline: 3.3365x; 1.4774x over previous
//
#include <hip/hip_runtime.h>
#include <stdint.h>

#define NND 50000
#define NNDP 50016            // table row-stride (sentinel zero row at index NND)
#define NE  1600000
#define INC 129
#define TP  25
#define NTR 25000
#define MPAD 50048
#define NC 192
#define NB_SCAN 196           // ceil(50000/256)
#define CSR_MAX (NE + 8*NND + 128)

typedef short bf16x8 __attribute__((ext_vector_type(8)));
typedef float f32x4 __attribute__((ext_vector_type(4)));

__device__ __forceinline__ uint32_t f2bf(float f){
  union{float ff; uint32_t u;} v; v.ff=f;
  return (v.u + 0x7FFFu + ((v.u>>16)&1u))>>16;
}
__device__ __forceinline__ uint32_t pack2(float a, float b){
  return f2bf(a) | (f2bf(b)<<16);
}
__device__ __forceinline__ float sigm(float v){ return 1.f/(1.f+__expf(-v)); }

// ---------------- weight prep: Weff = W_g @ Wl_g[:64], stacked+transposed ----
__global__ void k_prep(const float* Wz, const float* bz, const float* Wlz, const float* blz,
                       const float* Wr, const float* br, const float* Wlr, const float* blr,
                       const float* Wh, const float* bh, const float* Wlh, const float* blh,
                       uint16_t* BT, float* ceff, uint16_t* WlhT)
{
  int idx = blockIdx.x*256 + threadIdx.x;
  if (idx < NC*224) {
    int j = idx / 224, k = idx - j*224;
    int g = j >> 6, jj = j & 63;
    const float* W  = g==0?Wz :(g==1?Wr :Wh);
    const float* Wl = g==0?Wlz:(g==1?Wlr:Wlh);
    float v = 0.f;
    if (k < INC) {
      for (int m=0;m<64;m++) v += W[k*64+m]*Wl[m*64+jj];
    } else if (k >= 160) {
      int kk = k-160;
      v = (g<2) ? Wl[(64+kk)*64 + jj] : 0.f;
    }
    BT[idx] = (uint16_t)f2bf(v);
  } else if (idx < NC*224 + 64*64) {
    int t = idx - NC*224; int j = t>>6, k = t&63;   // WlhT[j][k] = Wl_h[64+k][j]
    WlhT[t] = (uint16_t)f2bf(Wlh[(64+k)*64 + j]);
  } else if (idx < NC*224 + 64*64 + NC) {
    int j = idx - NC*224 - 64*64;
    int g = j>>6, jj = j&63;
    const float* b  = g==0?bz :(g==1?br :bh);
    const float* Wl = g==0?Wlz:(g==1?Wlr:Wlh);
    const float* bl = g==0?blz:(g==1?blr:blh);
    float v = bl[jj];
    for (int m=0;m<64;m++) v += b[m]*Wl[m*64+jj];
    ceff[j] = v;
  }
}

__global__ void k_probs(const float* att, float* probs){
  if (threadIdx.x==0 && blockIdx.x==0){
    float m=-1e30f;
    for (int i=0;i<TP;i++) m = fmaxf(m, att[i]);
    float e[TP]; float s=0.f;
    for (int i=0;i<TP;i++){ e[i]=__expf(att[i]-m); s+=e[i]; }
    for (int i=0;i<TP;i++) probs[i]=e[i]/s;
  }
}

__global__ void k_hist(const int* eidx, int* deg){
  int e = blockIdx.x*256 + threadIdx.x;
  if (e < NE) atomicAdd(&deg[eidx[NE + e]], 1);   // dst row
}

__global__ void k_dinv(const int* deg, float* dinv){
  int n = blockIdx.x*256 + threadIdx.x;
  if (n < NND) dinv[n] = rsqrtf(1.0f + (float)deg[n]);
}

// ---- scan of padded row sizes p_i = (deg_i+1 rounded up to mult of 8) ----
__global__ void k_scan1(const int* deg, int* row_ptr, int* bsum){
  __shared__ int s[256];
  int tid = threadIdx.x;
  int i = blockIdx.x*256 + tid;
  int v = (i < NND) ? ((deg[i]+8)&~7) : 0;
  s[tid] = v; __syncthreads();
  for (int d=1; d<256; d<<=1){
    int t = (tid>=d) ? s[tid-d] : 0;
    __syncthreads();
    s[tid] += t; __syncthreads();
  }
  if (i < NND) row_ptr[i] = s[tid] - v;
  if (tid == 255) bsum[blockIdx.x] = s[255];
}
__global__ void k_scan2(int* bsum, int* boff, int* row_ptr){
  __shared__ int s[256];
  int tid = threadIdx.x;
  int v = (tid < NB_SCAN) ? bsum[tid] : 0;
  s[tid] = v; __syncthreads();
  for (int d=1; d<256; d<<=1){
    int t = (tid>=d) ? s[tid-d] : 0;
    __syncthreads();
    s[tid] += t; __syncthreads();
  }
  if (tid < NB_SCAN) boff[tid] = s[tid] - v;
  if (tid == NB_SCAN-1) row_ptr[NND] = s[tid];
}
__global__ void k_scan3(int* row_ptr, const int* boff){
  int i = blockIdx.x*256 + threadIdx.x;
  if (i < NND) row_ptr[i] += boff[blockIdx.x];
}

__global__ void k_fill(const int* eidx, const int* rp, int* cnt, uint16_t* csr){
  int e = blockIdx.x*256 + threadIdx.x;
  if (e < NE){
    int s = eidx[e], d = eidx[NE+e];
    int pos = rp[d] + atomicAdd(&cnt[d],1);
    csr[pos] = (uint16_t)s;
  }
}
// self-loop entry + sentinel padding (src=NND -> zero table row)
__global__ void k_self(const int* rp, const int* deg, uint16_t* csr){
  int n = blockIdx.x*256 + threadIdx.x;
  if (n < NND){
    int base = rp[n] + deg[n];
    int endp = rp[n+1];
    csr[base] = (uint16_t)n;
    for (int j=base+1; j<endp; j++) csr[j] = (uint16_t)NND;
  }
}

// x (N,129,25) fp32 -> tables pre-scaled by dinv[n]:
//   xT2[t][n][64 uints]  (ch 0..127 bf16 pairs, 256B rows)
//   xsl[t][n] f32        (ch 128)
__global__ __launch_bounds__(256) void k_transpose3(const float* __restrict__ x,
                                                    const float* __restrict__ dinv,
                                                    uint32_t* __restrict__ xT2,
                                                    float* __restrict__ xsl){
  __shared__ float lx[3232];           // 129*25 = 3225
  int n = blockIdx.x;
  const float* xr = x + (size_t)n*(INC*TP);
  for (int e=threadIdx.x; e<INC*TP; e+=256) lx[e] = xr[e];
  __syncthreads();
  float dv = dinv[n];
  for (int idx=threadIdx.x; idx<TP*64; idx+=256){
    int t = idx>>6, u = idx&63;
    int c0 = u*2;
    float v0 = lx[c0*TP+t]*dv, v1 = lx[(c0+1)*TP+t]*dv;
    xT2[((size_t)t*NNDP + n)*64 + u] = pack2(v0,v1);
  }
  for (int t=threadIdx.x; t<TP; t+=256)
    xsl[(size_t)t*NNDP + n] = dv*lx[128*TP + t];
  if (blockIdx.x == 0){                // zero the sentinel rows
    for (int idx=threadIdx.x; idx<TP*64; idx+=256){
      int t = idx>>6, u = idx&63;
      xT2[((size_t)t*NNDP + NND)*64 + u] = 0u;
    }
    for (int t=threadIdx.x; t<TP; t+=256) xsl[(size_t)t*NNDP + NND] = 0.f;
  }
}

// Aggregation, scheme D: wave per (dst,t); edges serial; per edge ONE
// wave-uniform coalesced 256B row load (lane = channel pair), scalar CSR
// via s_load (readfirstlane-pinned), scalar row base -> saddr loads.
__global__ __launch_bounds__(256) void k_agg(const uint32_t* __restrict__ xT2,
    const int* __restrict__ rp, const uint16_t* __restrict__ csr,
    const float* __restrict__ dinv, uint32_t* __restrict__ AX)
{
  int t = blockIdx.y;
  int wave = threadIdx.x>>6, lane = threadIdx.x&63;
  int d = blockIdx.x*4 + wave;
  int beg = __builtin_amdgcn_readfirstlane(rp[d]);
  int end = __builtin_amdgcn_readfirstlane(rp[d+1]);
  const uint32_t* tbl = xT2 + (size_t)t*((size_t)NNDP*64);
  float a0=0.f, a1=0.f;
  for (int i0=beg; i0<end; i0+=8){
    ulonglong2 c = *(const ulonglong2*)(csr + i0);   // uniform -> s_load
    #pragma unroll
    for (int k=0;k<4;k++){
      int s0 = (int)((c.x >> (k*16)) & 0xFFFFu);     // scalar extracts
      int s1 = (int)((c.y >> (k*16)) & 0xFFFFu);
      uint32_t u0 = tbl[(size_t)s0*64 + lane];       // coalesced 256B row
      uint32_t u1 = tbl[(size_t)s1*64 + lane];
      a0 += __int_as_float((int)(u0<<16));
      a1 += __int_as_float((int)(u0 & 0xFFFF0000u));
      a0 += __int_as_float((int)(u1<<16));
      a1 += __int_as_float((int)(u1 & 0xFFFF0000u));
    }
  }
  float dv = dinv[d];
  AX[(size_t)t*((size_t)MPAD*80) + (size_t)d*80 + lane] = pack2(dv*a0, dv*a1);
}

// channel 128: thread per (dst,t), gathers from L2-resident 200KB f32 plane
__global__ void k_aggL(const float* __restrict__ xsl,
    const int* __restrict__ rp, const uint16_t* __restrict__ csr,
    const float* __restrict__ dinv, uint32_t* __restrict__ AX)
{
  int t = blockIdx.y;
  int d = blockIdx.x*256 + threadIdx.x;
  if (d >= NND) return;
  const float* pl = xsl + (size_t)t*NNDP;
  float a = 0.f;
  int beg=rp[d], end=rp[d+1];
  #pragma unroll 4
  for (int i=beg;i<end;i++) a += pl[(int)csr[i]];
  AX[(size_t)t*((size_t)MPAD*80) + (size_t)d*80 + 64] = pack2(dinv[d]*a, 0.f);
}

// Fused full recurrence: block owns 64 nodes for ALL 25 steps.
// Per step: [AX|H](64x224) @ BT(224x192) -> Z,R,Ph; HR=H*R -> LDS;
// HR @ WlhT; GRU update in registers; attention accum in registers.
// H carried as f32 in regs (C-fragment) + bf16 in lA H-columns (A-fragment).
__global__ __launch_bounds__(256) void k_gru(const uint32_t* __restrict__ AX,
    const uint32_t* __restrict__ BT, const float* __restrict__ ceff,
    const uint32_t* __restrict__ WlhTu, float* __restrict__ accum,
    const float* __restrict__ probs)
{
  __shared__ __align__(16) uint32_t lA[64*116];
  __shared__ __align__(16) uint32_t lB[64*116];
  uint32_t* lW = lA;                    // alias: lA cols 0..35, dead after GEMM1
  uint16_t* lHR = (uint16_t*)lB;        // alias: row stride 88 elems
  uint16_t* lAh = (uint16_t*)lA;        // 16-bit view for H-col writes
  int tid = threadIdx.x;
  int n0 = blockIdx.x*64;
  int wave=tid>>6, lane=tid&63;
  int col16 = lane&15, kgrp = lane>>4;
  int arow = wave*16 + col16;
  int rbase = wave*16 + kgrp*4;

  // H columns (uints 80..111) start at zero (H0 = 0)
  for (int idx=tid; idx<64*32; idx+=256){
    int r=idx>>5, cu=idx&31;
    lA[r*116 + 80 + cu] = 0u;
  }

  f32x4 h[4] = {{0,0,0,0},{0,0,0,0},{0,0,0,0},{0,0,0,0}};
  f32x4 acr[4] = {{0,0,0,0},{0,0,0,0},{0,0,0,0},{0,0,0,0}};

  for (int t=0; t<TP; t++){
    const uint32_t* AXt = AX + (size_t)t*((size_t)MPAD*80);
    __syncthreads();   // prior step done reading lA/lB (and t=0 H-init done)
    for (int idx=tid; idx<64*80; idx+=256){
      int r = idx/80, cu = idx - r*80;
      lA[r*116+cu] = AXt[(size_t)(n0+r)*80 + cu];
    }
    for (int idx=tid; idx<64*112; idx+=256){
      int r = idx/112, cu = idx - r*112;
      lB[r*116+cu] = BT[(size_t)r*112 + cu];
    }
    __syncthreads();

    f32x4 accg[3][4] = {};
    #pragma unroll
    for (int g=0; g<3; g++){
      #pragma unroll
      for (int kk=0; kk<7; kk++){
        bf16x8 a = *(const bf16x8*)&lA[arow*116 + kk*16 + kgrp*4];
        #pragma unroll
        for (int cc=0; cc<4; cc++){
          bf16x8 b = *(const bf16x8*)&lB[(cc*16 + col16)*116 + kk*16 + kgrp*4];
          accg[g][cc] = __builtin_amdgcn_mfma_f32_16x16x32_bf16(a,b,accg[g][cc],0,0,0);
        }
      }
      if (g<2){
        __syncthreads();
        for (int idx=tid; idx<64*112; idx+=256){
          int r = idx/112, cu = idx - r*112;
          lB[r*116+cu] = BT[(size_t)(g+1)*64*112 + (size_t)r*112 + cu];
        }
        __syncthreads();
      }
    }
    __syncthreads();   // all MFMAs done with lA/lB before aliasing

    // epilogue A: gates; HR -> LDS; WlhT -> lW
    #pragma unroll
    for (int cc=0;cc<4;cc++){
      #pragma unroll
      for (int j=0;j<4;j++){
        int rl = rbase + j;
        int jl = cc*16 + col16;
        float z  = sigm(accg[0][cc][j] + ceff[jl]);
        float r  = sigm(accg[1][cc][j] + ceff[64+jl]);
        float ph = accg[2][cc][j] + ceff[128+jl];
        accg[0][cc][j] = z;
        accg[2][cc][j] = ph;
        lHR[rl*88 + jl] = (uint16_t)f2bf(h[cc][j]*r);
      }
    }
    for (int idx=tid; idx<64*32; idx+=256){
      int r=idx>>5, cu=idx&31;
      lW[r*36+cu] = WlhTu[r*32+cu];
    }
    __syncthreads();

    // GEMM2: HR @ WlhT
    f32x4 acc2[4] = {};
    #pragma unroll
    for (int kk=0;kk<2;kk++){
      bf16x8 a = *(const bf16x8*)&lHR[arow*88 + kk*32 + kgrp*8];
      #pragma unroll
      for (int cc=0;cc<4;cc++){
        bf16x8 b = *(const bf16x8*)&lW[(cc*16+col16)*36 + kk*16 + kgrp*4];
        acc2[cc]=__builtin_amdgcn_mfma_f32_16x16x32_bf16(a,b,acc2[cc],0,0,0);
      }
    }

    // epilogue B: GRU update; H (f32) in regs; H (bf16) -> lA H-cols; accum in regs
    float pt = probs[t];
    #pragma unroll
    for (int cc=0;cc<4;cc++){
      #pragma unroll
      for (int j=0;j<4;j++){
        int rl = rbase + j;
        int jl = cc*16+col16;
        float ht = tanhf(acc2[cc][j] + accg[2][cc][j]);
        float z = accg[0][cc][j];
        float hn = z*h[cc][j] + (1.f-z)*ht;
        h[cc][j] = hn;
        acr[cc][j] += pt*hn;
        lAh[rl*232 + 160 + jl] = (uint16_t)f2bf(hn);
      }
    }
  }

  // write attention accumulator once
  #pragma unroll
  for (int cc=0;cc<4;cc++){
    #pragma unroll
    for (int j=0;j<4;j++){
      int n = n0 + rbase + j;
      if (n < NND)
        accum[(size_t)n*64 + cc*16 + col16] = acr[cc][j];
    }
  }
}

__global__ void k_out(const int* train_idx, const float* accum, const float* Wo,
                      const float* bo, const float* y, float* out){
  int i = blockIdx.x*256 + threadIdx.x;
  if (i < NTR){
    int n = train_idx[i];
    float s = bo[0];
    const float* ar = accum + (size_t)n*64;
    #pragma unroll
    for (int j=0;j<64;j++) s += ar[j]*Wo[j];
    out[i] = sigm(s);
    out[NTR+i] = y[n];
  }
}

extern "C" void kernel_launch(void* const* d_in, const int* in_sizes, int n_in,
                              void* d_out, int out_size, void* d_ws, size_t ws_size,
                              hipStream_t stream)
{
  const float* x   = (const float*)d_in[0];
  const int*   eix = (const int*)d_in[1];
  const float* y   = (const float*)d_in[2];
  const int*   tri = (const int*)d_in[3];
  const float* Wz  = (const float*)d_in[4];
  const float* bz  = (const float*)d_in[5];
  const float* Wlz = (const float*)d_in[6];
  const float* blz = (const float*)d_in[7];
  const float* Wr  = (const float*)d_in[8];
  const float* br  = (const float*)d_in[9];
  const float* Wlr = (const float*)d_in[10];
  const float* blr = (const float*)d_in[11];
  const float* Wh  = (const float*)d_in[12];
  const float* bh  = (const float*)d_in[13];
  const float* Wlh = (const float*)d_in[14];
  const float* blh = (const float*)d_in[15];
  const float* att = (const float*)d_in[16];
  const float* Wo  = (const float*)d_in[17];
  const float* bo  = (const float*)d_in[18];
  float* out = (float*)d_out;

  char* w = (char*)d_ws;
  size_t off = 0;
  auto alloc = [&](size_t sz)->size_t{ size_t o=off; off=(off+sz+255)&~(size_t)255; return o; };

  // --- zero block (one small memset) ---
  size_t zo = off;
  size_t o_deg   = alloc((size_t)NND*4);
  size_t o_cnt   = alloc((size_t)NND*4);
  size_t zlen = off - zo;
  // --- rest ---
  size_t o_dinv  = alloc((size_t)NND*4);
  size_t o_rp    = alloc((size_t)(NND+1)*4);
  size_t o_bsum  = alloc((size_t)NB_SCAN*4);
  size_t o_boff  = alloc((size_t)NB_SCAN*4);
  size_t o_csr   = alloc((size_t)CSR_MAX*2);
  size_t o_BT    = alloc((size_t)NC*224*2);
  size_t o_ceff  = alloc((size_t)NC*4);
  size_t o_WlhT  = alloc((size_t)64*64*2);
  size_t o_probs = alloc((size_t)TP*4);
  size_t o_accum = alloc((size_t)MPAD*64*4);
  size_t o_AX    = alloc((size_t)TP*MPAD*80*4);   // 400 MB, all t
  size_t o_xT2   = alloc((size_t)TP*NNDP*256);    // 320 MB
  size_t o_xl    = alloc((size_t)TP*NNDP*4);      // 5 MB
  (void)ws_size; (void)in_sizes; (void)n_in; (void)out_size;

  int*      deg   = (int*)(w+o_deg);
  int*      cnt   = (int*)(w+o_cnt);
  float*    dinv  = (float*)(w+o_dinv);
  int*      rp    = (int*)(w+o_rp);
  int*      bsum  = (int*)(w+o_bsum);
  int*      boff  = (int*)(w+o_boff);
  uint16_t* csr   = (uint16_t*)(w+o_csr);
  uint16_t* BT    = (uint16_t*)(w+o_BT);
  float*    ceff  = (float*)(w+o_ceff);
  uint16_t* WlhT  = (uint16_t*)(w+o_WlhT);
  float*    probs = (float*)(w+o_probs);
  float*    accum = (float*)(w+o_accum);
  uint32_t* AX    = (uint32_t*)(w+o_AX);
  uint32_t* xT2   = (uint32_t*)(w+o_xT2);
  float*    xsl   = (float*)(w+o_xl);

  hipMemsetAsync(w+zo, 0, zlen, stream);

  k_prep<<<(NC*224 + 64*64 + NC + 255)/256, 256, 0, stream>>>(
      Wz,bz,Wlz,blz, Wr,br,Wlr,blr, Wh,bh,Wlh,blh, BT, ceff, WlhT);
  k_probs<<<1, 64, 0, stream>>>(att, probs);
  k_hist<<<(NE+255)/256, 256, 0, stream>>>(eix, deg);
  k_dinv<<<(NND+255)/256, 256, 0, stream>>>(deg, dinv);
  k_scan1<<<NB_SCAN, 256, 0, stream>>>(deg, rp, bsum);
  k_scan2<<<1, 256, 0, stream>>>(bsum, boff, rp);
  k_scan3<<<NB_SCAN, 256, 0, stream>>>(rp, boff);
  k_fill<<<(NE+255)/256, 256, 0, stream>>>(eix, rp, cnt, csr);
  k_self<<<NB_SCAN, 256, 0, stream>>>(rp, deg, csr);
  k_transpose3<<<NND, 256, 0, stream>>>(x, dinv, xT2, xsl);

  k_agg <<<dim3(12500, TP), 256, 0, stream>>>(xT2, rp, csr, dinv, AX);
  k_aggL<<<dim3(NB_SCAN, TP), 256, 0, stream>>>(xsl, rp, csr, dinv, AX);

  k_gru<<<MPAD/64, 256, 0, stream>>>(AX, (const uint32_t*)BT, ceff,
                                     (const uint32_t*)WlhT, accum, probs);
  k_out<<<(NTR+255)/256, 256, 0, stream>>>(tri, accum, Wo, bo, y, out);
}

// Round 7
// 1927.895 us; speedup vs baseline: 4.0824x; 1.2236x over previous
//
#include <hip/hip_runtime.h>
#include <stdint.h>

#define NND 50000
#define NNDP 50016            // table row-stride (sentinel zero row at index NND)
#define NE  1600000
#define INC 129
#define TP  25
#define NTR 25000
#define MPAD 50048
#define NC 192
#define NB_SCAN 196           // ceil(50000/256)
#define CSR_MAX (NE + 8*NND + 128)

typedef short bf16x8 __attribute__((ext_vector_type(8)));
typedef float f32x4 __attribute__((ext_vector_type(4)));
typedef float f32x2 __attribute__((ext_vector_type(2)));

__device__ __forceinline__ uint32_t f2bf(float f){
  union{float ff; uint32_t u;} v; v.ff=f;
  return (v.u + 0x7FFFu + ((v.u>>16)&1u))>>16;
}
__device__ __forceinline__ uint32_t pack2(float a, float b){
  return f2bf(a) | (f2bf(b)<<16);
}
__device__ __forceinline__ float sigm(float v){ return 1.f/(1.f+__expf(-v)); }

// ---------------- weight prep: Weff = W_g @ Wl_g[:64], stacked+transposed ----
__global__ void k_prep(const float* Wz, const float* bz, const float* Wlz, const float* blz,
                       const float* Wr, const float* br, const float* Wlr, const float* blr,
                       const float* Wh, const float* bh, const float* Wlh, const float* blh,
                       uint16_t* BT, float* ceff, uint16_t* WlhT)
{
  int idx = blockIdx.x*256 + threadIdx.x;
  if (idx < NC*224) {
    int j = idx / 224, k = idx - j*224;
    int g = j >> 6, jj = j & 63;
    const float* W  = g==0?Wz :(g==1?Wr :Wh);
    const float* Wl = g==0?Wlz:(g==1?Wlr:Wlh);
    float v = 0.f;
    if (k < INC) {
      for (int m=0;m<64;m++) v += W[k*64+m]*Wl[m*64+jj];
    } else if (k >= 160) {
      int kk = k-160;
      v = (g<2) ? Wl[(64+kk)*64 + jj] : 0.f;
    }
    BT[idx] = (uint16_t)f2bf(v);
  } else if (idx < NC*224 + 64*64) {
    int t = idx - NC*224; int j = t>>6, k = t&63;   // WlhT[j][k] = Wl_h[64+k][j]
    WlhT[t] = (uint16_t)f2bf(Wlh[(64+k)*64 + j]);
  } else if (idx < NC*224 + 64*64 + NC) {
    int j = idx - NC*224 - 64*64;
    int g = j>>6, jj = j&63;
    const float* b  = g==0?bz :(g==1?br :bh);
    const float* Wl = g==0?Wlz:(g==1?Wlr:Wlh);
    const float* bl = g==0?blz:(g==1?blr:blh);
    float v = bl[jj];
    for (int m=0;m<64;m++) v += b[m]*Wl[m*64+jj];
    ceff[j] = v;
  }
}

__global__ void k_probs(const float* att, float* probs){
  if (threadIdx.x==0 && blockIdx.x==0){
    float m=-1e30f;
    for (int i=0;i<TP;i++) m = fmaxf(m, att[i]);
    float e[TP]; float s=0.f;
    for (int i=0;i<TP;i++){ e[i]=__expf(att[i]-m); s+=e[i]; }
    for (int i=0;i<TP;i++) probs[i]=e[i]/s;
  }
}

__global__ void k_hist(const int* eidx, int* deg){
  int e = blockIdx.x*256 + threadIdx.x;
  if (e < NE) atomicAdd(&deg[eidx[NE + e]], 1);   // dst row
}

__global__ void k_dinv(const int* deg, float* dinv){
  int n = blockIdx.x*256 + threadIdx.x;
  if (n < NND) dinv[n] = rsqrtf(1.0f + (float)deg[n]);
}

// ---- scan of padded row sizes p_i = (deg_i+1 rounded up to mult of 8) ----
__global__ void k_scan1(const int* deg, int* row_ptr, int* bsum){
  __shared__ int s[256];
  int tid = threadIdx.x;
  int i = blockIdx.x*256 + tid;
  int v = (i < NND) ? ((deg[i]+8)&~7) : 0;
  s[tid] = v; __syncthreads();
  for (int d=1; d<256; d<<=1){
    int t = (tid>=d) ? s[tid-d] : 0;
    __syncthreads();
    s[tid] += t; __syncthreads();
  }
  if (i < NND) row_ptr[i] = s[tid] - v;
  if (tid == 255) bsum[blockIdx.x] = s[255];
}
__global__ void k_scan2(int* bsum, int* boff, int* row_ptr){
  __shared__ int s[256];
  int tid = threadIdx.x;
  int v = (tid < NB_SCAN) ? bsum[tid] : 0;
  s[tid] = v; __syncthreads();
  for (int d=1; d<256; d<<=1){
    int t = (tid>=d) ? s[tid-d] : 0;
    __syncthreads();
    s[tid] += t; __syncthreads();
  }
  if (tid < NB_SCAN) boff[tid] = s[tid] - v;
  if (tid == NB_SCAN-1) row_ptr[NND] = s[tid];
}
__global__ void k_scan3(int* row_ptr, const int* boff){
  int i = blockIdx.x*256 + threadIdx.x;
  if (i < NND) row_ptr[i] += boff[blockIdx.x];
}

__global__ void k_fill(const int* eidx, const int* rp, int* cnt, uint16_t* csr){
  int e = blockIdx.x*256 + threadIdx.x;
  if (e < NE){
    int s = eidx[e], d = eidx[NE+e];
    int pos = rp[d] + atomicAdd(&cnt[d],1);
    csr[pos] = (uint16_t)s;
  }
}
// self-loop entry + sentinel padding (src=NND -> zero table row)
__global__ void k_self(const int* rp, const int* deg, uint16_t* csr){
  int n = blockIdx.x*256 + threadIdx.x;
  if (n < NND){
    int base = rp[n] + deg[n];
    int endp = rp[n+1];
    csr[base] = (uint16_t)n;
    for (int j=base+1; j<endp; j++) csr[j] = (uint16_t)NND;
  }
}

// x (N,129,25) fp32 -> tables pre-scaled by dinv[n]:
//   xT8[t][n][32 uints]  (ch 0..127 as fp8 e4m3, 128B rows = 1 cache line)
//   xsl[t][n] f32        (ch 128, exact)
__global__ __launch_bounds__(256) void k_transpose3(const float* __restrict__ x,
                                                    const float* __restrict__ dinv,
                                                    uint32_t* __restrict__ xT8,
                                                    float* __restrict__ xsl){
  __shared__ float lx[3232];           // 129*25 = 3225
  int n = blockIdx.x;
  const float* xr = x + (size_t)n*(INC*TP);
  for (int e=threadIdx.x; e<INC*TP; e+=256) lx[e] = xr[e];
  __syncthreads();
  float dv = dinv[n];
  for (int idx=threadIdx.x; idx<TP*32; idx+=256){
    int t = idx>>5, u = idx&31;
    int c0 = u*4;
    float v0 = lx[(c0+0)*TP+t]*dv, v1 = lx[(c0+1)*TP+t]*dv;
    float v2 = lx[(c0+2)*TP+t]*dv, v3 = lx[(c0+3)*TP+t]*dv;
    int wlo = __builtin_amdgcn_cvt_pk_fp8_f32(v0, v1, 0, false);
    int w   = __builtin_amdgcn_cvt_pk_fp8_f32(v2, v3, wlo, true);
    xT8[((size_t)t*NNDP + n)*32 + u] = (uint32_t)w;
  }
  for (int t=threadIdx.x; t<TP; t+=256)
    xsl[(size_t)t*NNDP + n] = dv*lx[128*TP + t];
  if (blockIdx.x == 0){                // zero the sentinel rows
    for (int idx=threadIdx.x; idx<TP*32; idx+=256){
      int t = idx>>5, u = idx&31;
      xT8[((size_t)t*NNDP + NND)*32 + u] = 0u;
    }
    for (int t=threadIdx.x; t<TP; t+=256) xsl[(size_t)t*NNDP + NND] = 0.f;
  }
}

// Aggregation, scheme D + fp8: wave per (dst,t); edges serial; per edge ONE
// wave-uniform coalesced 128B row load (lane = fp8 channel pair via ushort),
// scalar CSR via s_load, HW cvt_pk_f32_fp8 decode, scalar row base.
__global__ __launch_bounds__(256) void k_agg(const uint16_t* __restrict__ xT8,
    const int* __restrict__ rp, const uint16_t* __restrict__ csr,
    const float* __restrict__ dinv, uint32_t* __restrict__ AX)
{
  int t = blockIdx.y;
  int wave = threadIdx.x>>6, lane = threadIdx.x&63;
  int d = blockIdx.x*4 + wave;
  int beg = __builtin_amdgcn_readfirstlane(rp[d]);
  int end = __builtin_amdgcn_readfirstlane(rp[d+1]);
  const uint16_t* tbl = xT8 + (size_t)t*((size_t)NNDP*64);   // 64 ushorts/row
  float a0=0.f, a1=0.f;
  for (int i0=beg; i0<end; i0+=8){
    ulonglong2 c = *(const ulonglong2*)(csr + i0);   // uniform -> s_load
    #pragma unroll
    for (int k=0;k<4;k++){
      int s0 = (int)((c.x >> (k*16)) & 0xFFFFu);     // scalar extracts
      int s1 = (int)((c.y >> (k*16)) & 0xFFFFu);
      uint32_t u0 = tbl[(size_t)s0*64 + lane];       // 128B row, 1 line
      uint32_t u1 = tbl[(size_t)s1*64 + lane];
      f32x2 v0 = __builtin_amdgcn_cvt_pk_f32_fp8((int)u0, false);
      f32x2 v1 = __builtin_amdgcn_cvt_pk_f32_fp8((int)u1, false);
      a0 += v0.x; a1 += v0.y;
      a0 += v1.x; a1 += v1.y;
    }
  }
  float dv = dinv[d];
  AX[(size_t)t*((size_t)MPAD*80) + (size_t)d*80 + lane] = pack2(dv*a0, dv*a1);
}

// channel 128: thread per (dst,t), gathers from L2-resident 200KB f32 plane
__global__ void k_aggL(const float* __restrict__ xsl,
    const int* __restrict__ rp, const uint16_t* __restrict__ csr,
    const float* __restrict__ dinv, uint32_t* __restrict__ AX)
{
  int t = blockIdx.y;
  int d = blockIdx.x*256 + threadIdx.x;
  if (d >= NND) return;
  const float* pl = xsl + (size_t)t*NNDP;
  float a = 0.f;
  int beg=rp[d], end=rp[d+1];
  #pragma unroll 4
  for (int i=beg;i<end;i++) a += pl[(int)csr[i]];
  AX[(size_t)t*((size_t)MPAD*80) + (size_t)d*80 + 64] = pack2(dinv[d]*a, 0.f);
}

// Fused full recurrence: block owns 64 nodes for ALL 25 steps.
// Per step: [AX|H](64x224) @ BT(224x192) -> Z,R,Ph; HR=H*R -> LDS;
// HR @ WlhT; GRU update in registers; attention accum in registers.
__global__ __launch_bounds__(256) void k_gru(const uint32_t* __restrict__ AX,
    const uint32_t* __restrict__ BT, const float* __restrict__ ceff,
    const uint32_t* __restrict__ WlhTu, float* __restrict__ accum,
    const float* __restrict__ probs)
{
  __shared__ __align__(16) uint32_t lA[64*116];
  __shared__ __align__(16) uint32_t lB[64*116];
  uint32_t* lW = lA;                    // alias: lA cols 0..35, dead after GEMM1
  uint16_t* lHR = (uint16_t*)lB;        // alias: row stride 88 elems
  uint16_t* lAh = (uint16_t*)lA;        // 16-bit view for H-col writes
  int tid = threadIdx.x;
  int n0 = blockIdx.x*64;
  int wave=tid>>6, lane=tid&63;
  int col16 = lane&15, kgrp = lane>>4;
  int arow = wave*16 + col16;
  int rbase = wave*16 + kgrp*4;

  // H columns (uints 80..111) start at zero (H0 = 0)
  for (int idx=tid; idx<64*32; idx+=256){
    int r=idx>>5, cu=idx&31;
    lA[r*116 + 80 + cu] = 0u;
  }

  f32x4 h[4] = {{0,0,0,0},{0,0,0,0},{0,0,0,0},{0,0,0,0}};
  f32x4 acr[4] = {{0,0,0,0},{0,0,0,0},{0,0,0,0},{0,0,0,0}};

  for (int t=0; t<TP; t++){
    const uint32_t* AXt = AX + (size_t)t*((size_t)MPAD*80);
    __syncthreads();   // prior step done reading lA/lB (and t=0 H-init done)
    for (int idx=tid; idx<64*80; idx+=256){
      int r = idx/80, cu = idx - r*80;
      lA[r*116+cu] = AXt[(size_t)(n0+r)*80 + cu];
    }
    for (int idx=tid; idx<64*112; idx+=256){
      int r = idx/112, cu = idx - r*112;
      lB[r*116+cu] = BT[(size_t)r*112 + cu];
    }
    __syncthreads();

    f32x4 accg[3][4] = {};
    #pragma unroll
    for (int g=0; g<3; g++){
      #pragma unroll
      for (int kk=0; kk<7; kk++){
        bf16x8 a = *(const bf16x8*)&lA[arow*116 + kk*16 + kgrp*4];
        #pragma unroll
        for (int cc=0; cc<4; cc++){
          bf16x8 b = *(const bf16x8*)&lB[(cc*16 + col16)*116 + kk*16 + kgrp*4];
          accg[g][cc] = __builtin_amdgcn_mfma_f32_16x16x32_bf16(a,b,accg[g][cc],0,0,0);
        }
      }
      if (g<2){
        __syncthreads();
        for (int idx=tid; idx<64*112; idx+=256){
          int r = idx/112, cu = idx - r*112;
          lB[r*116+cu] = BT[(size_t)(g+1)*64*112 + (size_t)r*112 + cu];
        }
        __syncthreads();
      }
    }
    __syncthreads();   // all MFMAs done with lA/lB before aliasing

    // epilogue A: gates; HR -> LDS; WlhT -> lW
    #pragma unroll
    for (int cc=0;cc<4;cc++){
      #pragma unroll
      for (int j=0;j<4;j++){
        int rl = rbase + j;
        int jl = cc*16 + col16;
        float z  = sigm(accg[0][cc][j] + ceff[jl]);
        float r  = sigm(accg[1][cc][j] + ceff[64+jl]);
        float ph = accg[2][cc][j] + ceff[128+jl];
        accg[0][cc][j] = z;
        accg[2][cc][j] = ph;
        lHR[rl*88 + jl] = (uint16_t)f2bf(h[cc][j]*r);
      }
    }
    for (int idx=tid; idx<64*32; idx+=256){
      int r=idx>>5, cu=idx&31;
      lW[r*36+cu] = WlhTu[r*32+cu];
    }
    __syncthreads();

    // GEMM2: HR @ WlhT
    f32x4 acc2[4] = {};
    #pragma unroll
    for (int kk=0;kk<2;kk++){
      bf16x8 a = *(const bf16x8*)&lHR[arow*88 + kk*32 + kgrp*8];
      #pragma unroll
      for (int cc=0;cc<4;cc++){
        bf16x8 b = *(const bf16x8*)&lW[(cc*16+col16)*36 + kk*16 + kgrp*4];
        acc2[cc]=__builtin_amdgcn_mfma_f32_16x16x32_bf16(a,b,acc2[cc],0,0,0);
      }
    }

    // epilogue B: GRU update; H (f32) in regs; H (bf16) -> lA H-cols; accum in regs
    float pt = probs[t];
    #pragma unroll
    for (int cc=0;cc<4;cc++){
      #pragma unroll
      for (int j=0;j<4;j++){
        int rl = rbase + j;
        int jl = cc*16+col16;
        float ht = tanhf(acc2[cc][j] + accg[2][cc][j]);
        float z = accg[0][cc][j];
        float hn = z*h[cc][j] + (1.f-z)*ht;
        h[cc][j] = hn;
        acr[cc][j] += pt*hn;
        lAh[rl*232 + 160 + jl] = (uint16_t)f2bf(hn);
      }
    }
  }

  // write attention accumulator once
  #pragma unroll
  for (int cc=0;cc<4;cc++){
    #pragma unroll
    for (int j=0;j<4;j++){
      int n = n0 + rbase + j;
      if (n < NND)
        accum[(size_t)n*64 + cc*16 + col16] = acr[cc][j];
    }
  }
}

__global__ void k_out(const int* train_idx, const float* accum, const float* Wo,
                      const float* bo, const float* y, float* out){
  int i = blockIdx.x*256 + threadIdx.x;
  if (i < NTR){
    int n = train_idx[i];
    float s = bo[0];
    const float* ar = accum + (size_t)n*64;
    #pragma unroll
    for (int j=0;j<64;j++) s += ar[j]*Wo[j];
    out[i] = sigm(s);
    out[NTR+i] = y[n];
  }
}

extern "C" void kernel_launch(void* const* d_in, const int* in_sizes, int n_in,
                              void* d_out, int out_size, void* d_ws, size_t ws_size,
                              hipStream_t stream)
{
  const float* x   = (const float*)d_in[0];
  const int*   eix = (const int*)d_in[1];
  const float* y   = (const float*)d_in[2];
  const int*   tri = (const int*)d_in[3];
  const float* Wz  = (const float*)d_in[4];
  const float* bz  = (const float*)d_in[5];
  const float* Wlz = (const float*)d_in[6];
  const float* blz = (const float*)d_in[7];
  const float* Wr  = (const float*)d_in[8];
  const float* br  = (const float*)d_in[9];
  const float* Wlr = (const float*)d_in[10];
  const float* blr = (const float*)d_in[11];
  const float* Wh  = (const float*)d_in[12];
  const float* bh  = (const float*)d_in[13];
  const float* Wlh = (const float*)d_in[14];
  const float* blh = (const float*)d_in[15];
  const float* att = (const float*)d_in[16];
  const float* Wo  = (const float*)d_in[17];
  const float* bo  = (const float*)d_in[18];
  float* out = (float*)d_out;

  char* w = (char*)d_ws;
  size_t off = 0;
  auto alloc = [&](size_t sz)->size_t{ size_t o=off; off=(off+sz+255)&~(size_t)255; return o; };

  // --- zero block (one small memset) ---
  size_t zo = off;
  size_t o_deg   = alloc((size_t)NND*4);
  size_t o_cnt   = alloc((size_t)NND*4);
  size_t zlen = off - zo;
  // --- rest ---
  size_t o_dinv  = alloc((size_t)NND*4);
  size_t o_rp    = alloc((size_t)(NND+1)*4);
  size_t o_bsum  = alloc((size_t)NB_SCAN*4);
  size_t o_boff  = alloc((size_t)NB_SCAN*4);
  size_t o_csr   = alloc((size_t)CSR_MAX*2);
  size_t o_BT    = alloc((size_t)NC*224*2);
  size_t o_ceff  = alloc((size_t)NC*4);
  size_t o_WlhT  = alloc((size_t)64*64*2);
  size_t o_probs = alloc((size_t)TP*4);
  size_t o_accum = alloc((size_t)MPAD*64*4);
  size_t o_AX    = alloc((size_t)TP*MPAD*80*4);   // 400 MB, all t
  size_t o_xT8   = alloc((size_t)TP*NNDP*128);    // 160 MB (fp8 table)
  size_t o_xl    = alloc((size_t)TP*NNDP*4);      // 5 MB
  (void)ws_size; (void)in_sizes; (void)n_in; (void)out_size;

  int*      deg   = (int*)(w+o_deg);
  int*      cnt   = (int*)(w+o_cnt);
  float*    dinv  = (float*)(w+o_dinv);
  int*      rp    = (int*)(w+o_rp);
  int*      bsum  = (int*)(w+o_bsum);
  int*      boff  = (int*)(w+o_boff);
  uint16_t* csr   = (uint16_t*)(w+o_csr);
  uint16_t* BT    = (uint16_t*)(w+o_BT);
  float*    ceff  = (float*)(w+o_ceff);
  uint16_t* WlhT  = (uint16_t*)(w+o_WlhT);
  float*    probs = (float*)(w+o_probs);
  float*    accum = (float*)(w+o_accum);
  uint32_t* AX    = (uint32_t*)(w+o_AX);
  uint32_t* xT8   = (uint32_t*)(w+o_xT8);
  float*    xsl   = (float*)(w+o_xl);

  hipMemsetAsync(w+zo, 0, zlen, stream);

  k_prep<<<(NC*224 + 64*64 + NC + 255)/256, 256, 0, stream>>>(
      Wz,bz,Wlz,blz, Wr,br,Wlr,blr, Wh,bh,Wlh,blh, BT, ceff, WlhT);
  k_probs<<<1, 64, 0, stream>>>(att, probs);
  k_hist<<<(NE+255)/256, 256, 0, stream>>>(eix, deg);
  k_dinv<<<(NND+255)/256, 256, 0, stream>>>(deg, dinv);
  k_scan1<<<NB_SCAN, 256, 0, stream>>>(deg, rp, bsum);
  k_scan2<<<1, 256, 0, stream>>>(bsum, boff, rp);
  k_scan3<<<NB_SCAN, 256, 0, stream>>>(rp, boff);
  k_fill<<<(NE+255)/256, 256, 0, stream>>>(eix, rp, cnt, csr);
  k_self<<<NB_SCAN, 256, 0, stream>>>(rp, deg, csr);
  k_transpose3<<<NND, 256, 0, stream>>>(x, dinv, xT8, xsl);

  k_agg <<<dim3(12500, TP), 256, 0, stream>>>((const uint16_t*)xT8, rp, csr, dinv, AX);
  k_aggL<<<dim3(NB_SCAN, TP), 256, 0, stream>>>(xsl, rp, csr, dinv, AX);

  k_gru<<<MPAD/64, 256, 0, stream>>>(AX, (const uint32_t*)BT, ceff,
                                     (const uint32_t*)WlhT, accum, probs);
  k_out<<<(NTR+255)/256, 256, 0, stream>>>(tri, accum, Wo, bo, y, out);
}